// Round 6
// baseline (475.415 us; speedup 1.0000x reference)
//
#include <hip/hip_runtime.h>

// ---------------- problem constants ----------------
#define T_TOK 16384
#define DM    512
#define DFF   2048
#define NE    8
#define NP    16
#define KP    4
#define RANK  64
#define KR    256           // KP * RANK
#define EPSF  1e-8f
#define CAP   6144          // per-expert pair capacity (expected ~4096)
#define MT_E  48            // CAP / 128 M-tiles per expert

typedef unsigned short u16;
typedef __bf16 bf16x8 __attribute__((ext_vector_type(8)));
typedef float  f32x4  __attribute__((ext_vector_type(4)));
typedef unsigned short u16x8v __attribute__((ext_vector_type(8)));
typedef unsigned short u16x4v __attribute__((ext_vector_type(4)));

typedef __attribute__((address_space(3))) void as3_void;
typedef __attribute__((address_space(1))) void as1_void;

__device__ __forceinline__ u16 f2bf(float f) {
  unsigned int u = __builtin_bit_cast(unsigned int, f);
  u += 0x7fffu + ((u >> 16) & 1u);          // round-to-nearest-even
  return (u16)(u >> 16);
}
__device__ __forceinline__ float bf2f(u16 v) {
  unsigned int u = ((unsigned int)v) << 16;
  return __builtin_bit_cast(float, u);
}

__device__ __forceinline__ void gl_lds16(const u16* g, u16* l) {
  __builtin_amdgcn_global_load_lds((as1_void*)g, (as3_void*)l, 16, 0, 0);
}

// ---- st_16x32 swizzle (m201, HW-verified on this exact read shape) ----
// byte' = byte ^ (((byte>>9)&1)<<5)  ==  col_elem ^= ((row>>2)&1)<<4 for
// 128 B rows. R1-R5 lesson: my (row&7)<<3 16B-granule XOR left ~8 lanes per
// bank-quad on every ds_read_b128 (~35 cyc/instr vs 12 conflict-free) — the
// ~2000 cyc/chunk-unit invariant across v4/v6/v7 was bank-conflict
// throughput, not latency. m201's 1-bit 32 B XOR measured 141x conflict drop
// at 62% MfmaUtil. Permutes within each 1024 B block -> gl_lds compatible
// (pre-swizzle SOURCE, dst linear). Readers XOR col with ((row>>2)&1)<<4;
// with row = base16 + ln this is the per-lane constant (ln&4)<<2.

// stage 128x64 bf16 tile into LDS (256-thread kernels)
__device__ __forceinline__ void stage_tile(const u16* g, int ld, u16* lds_tile, int tid) {
  int row = tid >> 3, cc = tid & 7;
#pragma unroll
  for (int ri = 0; ri < 4; ri++) {
    int rg = ri * 32 + row;
    gl_lds16(g + (size_t)rg * ld + ((cc ^ (((rg >> 2) & 1) << 1)) * 8),
             &lds_tile[rg * 64 + cc * 8]);
  }
}

// stage 128x64 bf16 tile into LDS (512-thread kernels): 1024 16B-chunks, 2/thread
__device__ __forceinline__ void stage_tile512(const u16* g, int ld, u16* lds_tile, int tid) {
#pragma unroll
  for (int ri = 0; ri < 2; ri++) {
    int i = ri * 512 + tid;                // chunk id 0..1023
    int row = i >> 3, cc = i & 7;
    gl_lds16(g + (size_t)row * ld + ((cc ^ (((row >> 2) & 1) << 1)) * 8),
             &lds_tile[i * 8]);
  }
}

// shared 128x128 MFMA inner step over one BK=64 LDS tile pair (256-thr kernels)
__device__ __forceinline__ void mfma_block(const u16* As, const u16* Bs, f32x4 acc[4][4],
                                           int wm, int wn, int ln, int quad) {
  int sw = (ln & 4) << 2;                  // st_16x32 read XOR
#pragma unroll
  for (int ks = 0; ks < 2; ks++) {
    bf16x8 af[4], bf[4];
    int co = (ks * 32 + quad * 8) ^ sw;
#pragma unroll
    for (int mt = 0; mt < 4; mt++)
      af[mt] = *(const bf16x8*)&As[(wm * 64 + mt * 16 + ln) * 64 + co];
#pragma unroll
    for (int nt = 0; nt < 4; nt++)
      bf[nt] = *(const bf16x8*)&Bs[(wn * 64 + nt * 16 + ln) * 64 + co];
#pragma unroll
    for (int mt = 0; mt < 4; mt++)
#pragma unroll
      for (int nt = 0; nt < 4; nt++)
        acc[mt][nt] = __builtin_amdgcn_mfma_f32_16x16x32_bf16(af[mt], bf[nt], acc[mt][nt], 0, 0, 0);
  }
}

// ---------------- zero counters ----------------
__global__ void zero_kernel(int* __restrict__ cnt, float* __restrict__ probsum) {
  int i = blockIdx.x * 256 + threadIdx.x;
  if (i < NE) cnt[i] = 0;
  if (i >= NE && i < NE + NE * 64) probsum[i - NE] = 0.f;
}

// ---------------- primitive-bank softmax + top-4 ----------------
__global__ void compose_meta(const float* __restrict__ fc1, const float* __restrict__ fc2,
                             float* __restrict__ sw1, int* __restrict__ idx1,
                             float* __restrict__ sw2, int* __restrict__ idx2) {
  int tid = threadIdx.x;
  if (tid >= 16) return;
  const float* src = (tid < 8) ? fc1 : fc2;
  float* sw = (tid < 8) ? sw1 : sw2;
  int*  idx = (tid < 8) ? idx1 : idx2;
  int e = tid & 7;
  float wv[NP];
  float mx = -1e30f;
  for (int p = 0; p < NP; p++) { wv[p] = src[e * NP + p]; mx = fmaxf(mx, wv[p]); }
  float sum = 0.f;
  for (int p = 0; p < NP; p++) { wv[p] = __expf(wv[p] - mx); sum += wv[p]; }
  float inv = 1.f / sum;
  for (int p = 0; p < NP; p++) wv[p] *= inv;
  float tw[KP]; int ti[KP];
  for (int k = 0; k < KP; k++) {
    int best = 0; float bv = -1.f;
    for (int p = 0; p < NP; p++) if (wv[p] > bv) { bv = wv[p]; best = p; }
    tw[k] = bv; ti[k] = best; wv[best] = -2.f;
  }
  float ts = tw[0] + tw[1] + tw[2] + tw[3];
  float invt = 1.f / (ts + EPSF);
  for (int k = 0; k < KP; k++) {
    sw[e * KP + k] = sqrtf(tw[k] * invt + EPSF);
    idx[e * KP + k] = ti[k];
  }
}

// ---------------- build W1/W2 via LDS transpose ----------------
__global__ __launch_bounds__(256) void build_AT(
    const float* __restrict__ A, const int* __restrict__ idx,
    const float* __restrict__ sw, u16* __restrict__ W, int D) {
  __shared__ u16 T[64 * 68];
  int ntile = D >> 6;
  int dt = blockIdx.x % ntile;
  int g  = blockIdx.x / ntile;      // e*4+k
  int p = idx[g]; float s = sw[g];
  int d0 = dt * 64;
  int tid = threadIdx.x;
  {
    int rr = (tid & 15) * 4, dd = tid >> 4;
#pragma unroll
    for (int pass = 0; pass < 4; pass++) {
      int d = pass * 16 + dd;
      float4 v = *(const float4*)(A + ((size_t)p * D + d0 + d) * 64 + rr);
      T[(rr + 0) * 68 + d] = f2bf(v.x * s);
      T[(rr + 1) * 68 + d] = f2bf(v.y * s);
      T[(rr + 2) * 68 + d] = f2bf(v.z * s);
      T[(rr + 3) * 68 + d] = f2bf(v.w * s);
    }
  }
  __syncthreads();
  int e = g >> 2, k = g & 3;
  int c = (tid & 15) * 4, r = tid >> 4;
#pragma unroll
  for (int pass = 0; pass < 4; pass++) {
    int rr = pass * 16 + r;
    u16x4v o;
#pragma unroll
    for (int j = 0; j < 4; j++) o[j] = T[rr * 68 + c + j];
    *(u16x4v*)&W[((size_t)e * KR + k * 64 + rr) * D + d0 + c] = o;
  }
}

// ---------------- build V1/V2 ----------------
__global__ void build_V(const float* __restrict__ B1, const float* __restrict__ B2,
                        const float* __restrict__ sw1, const int* __restrict__ idx1,
                        const float* __restrict__ sw2, const int* __restrict__ idx2,
                        u16* __restrict__ V1, u16* __restrict__ V2) {
  const int S2 = NE * DFF * KR;   // V1[e][f][kr] = B1[p][r][f]*s
  const int S4 = NE * DM * KR;    // V2[e][d][kr] = B2[p][r][d]*s
  int i = blockIdx.x * 256 + threadIdx.x;
  if (i < S2) {
    int kr = i & 255; int f = (i >> 8) & 2047; int e = i >> 19;
    int k = kr >> 6, r = kr & 63; int p = idx1[e * 4 + k];
    V1[i] = f2bf(B1[((size_t)p * RANK + r) * DFF + f] * sw1[e * 4 + k]);
  } else if (i < S2 + S4) {
    int j = i - S2;
    int kr = j & 255; int d = (j >> 8) & 511; int e = j >> 17;
    int k = kr >> 6, r = kr & 63; int p = idx2[e * 4 + k];
    V2[j] = f2bf(B2[((size_t)p * RANK + r) * DM + d] * sw2[e * 4 + k]);
  }
}

// ---------------- router, token-per-lane (k-split 4) ----------------
__global__ __launch_bounds__(256) void router_kernel(
    const float* __restrict__ x, const float* __restrict__ Wr,
    float* __restrict__ probsum, int* __restrict__ eidx,
    float* __restrict__ gate) {
  __shared__ float wr_s[NE * 4 * 132];
  __shared__ float ps_s[NE];
  int tid = threadIdx.x;
  if (tid < NE) ps_s[tid] = 0.f;
  for (int i = tid; i < NE * DM; i += 256) {
    int e = i >> 9, k = i & 511;
    wr_s[(e * 4 + (k >> 7)) * 132 + (k & 127)] = Wr[i];
  }
  __syncthreads();
  int lane = tid & 63, wv = tid >> 6;
  int tl = lane & 15, sl = lane >> 4;
  int t = blockIdx.x * 64 + wv * 16 + tl;
  const float* xp = x + (size_t)t * DM + sl * 128;
  const float* wp = &wr_s[sl * 132];
  float acc[NE];
#pragma unroll
  for (int e = 0; e < NE; e++) acc[e] = 0.f;
  for (int c = 0; c < 32; c++) {
    float4 xv = *(const float4*)(xp + c * 4);
#pragma unroll
    for (int e = 0; e < NE; e++) {
      float4 w4 = *(const float4*)(wp + e * 4 * 132 + c * 4);
      acc[e] += xv.x * w4.x + xv.y * w4.y + xv.z * w4.z + xv.w * w4.w;
    }
  }
#pragma unroll
  for (int e = 0; e < NE; e++) {
    acc[e] += __shfl_xor(acc[e], 16, 64);
    acc[e] += __shfl_xor(acc[e], 32, 64);
  }
  if (sl == 0) {
    float mx = acc[0];
#pragma unroll
    for (int e = 1; e < NE; e++) mx = fmaxf(mx, acc[e]);
    float pe[NE]; float sum = 0.f;
#pragma unroll
    for (int e = 0; e < NE; e++) { pe[e] = __expf(acc[e] - mx); sum += pe[e]; }
    float inv = 1.f / sum;
#pragma unroll
    for (int e = 0; e < NE; e++) pe[e] *= inv;
    int i0 = 0;
#pragma unroll
    for (int e = 1; e < NE; e++) if (pe[e] > pe[i0]) i0 = e;
    int i1 = (i0 == 0) ? 1 : 0;
#pragma unroll
    for (int e = 0; e < NE; e++) if (e != i0 && pe[e] > pe[i1]) i1 = e;
    float p0 = pe[i0], p1 = pe[i1];
    float gd = 1.f / (p0 + p1 + EPSF);
    eidx[t] = i0 | (i1 << 3);
    gate[i0 * T_TOK + t] = p0 * gd;
    gate[i1 * T_TOK + t] = p1 * gd;
#pragma unroll
    for (int e = 0; e < NE; e++) atomicAdd(&ps_s[e], pe[e]);
  }
  __syncthreads();
  if (tid < NE) atomicAdd(&probsum[tid * 64 + (blockIdx.x & 63)], ps_s[tid]);
}

// ---------------- scatter (block-aggregated cnt) + per-token slot pairs ----------
__global__ void scatter_kernel(const int* __restrict__ eidx,
                               int* __restrict__ cnt, int* __restrict__ perm,
                               int* __restrict__ slots) {
  __shared__ int hist[NE], base[NE];
  int tid = threadIdx.x;
  if (tid < NE) hist[tid] = 0;
  __syncthreads();
  int t = blockIdx.x * 256 + tid;
  int pk = eidx[t];
  int e0 = pk & 7, e1 = (pk >> 3) & 7;
  int p0 = atomicAdd(&hist[e0], 1);
  int p1 = atomicAdd(&hist[e1], 1);
  __syncthreads();
  if (tid < NE) base[tid] = atomicAdd(&cnt[tid], hist[tid]);
  __syncthreads();
  int g0 = base[e0] + p0; if (g0 >= CAP) g0 = CAP - 1;
  int g1 = base[e1] + p1; if (g1 >= CAP) g1 = CAP - 1;
  perm[e0 * T_TOK + g0] = t;
  perm[e1 * T_TOK + g1] = t;
  slots[t * 2]     = e0 * CAP + g0;
  slots[t * 2 + 1] = e1 * CAP + g1;
}

// ---------------- aux loss (one wave) ----------------
__global__ void aux_kernel(const int* __restrict__ cnt, const float* __restrict__ probsum,
                           float* __restrict__ aux_out) {
  int lane = threadIdx.x;
  if (lane >= 64) return;
  float s[NE];
#pragma unroll
  for (int e = 0; e < NE; e++) {
    float v = probsum[e * 64 + lane];
#pragma unroll
    for (int off = 32; off > 0; off >>= 1) v += __shfl_xor(v, off, 64);
    s[e] = v;
  }
  if (lane == 0) {
    float c[NE]; float cs = 0.f;
    for (int e = 0; e < NE; e++) { c[e] = (float)cnt[e]; cs += c[e]; }
    float aux = 0.f;
    for (int e = 0; e < NE; e++)
      aux += (c[e] / (cs + EPSF)) * (s[e] / (float)T_TOK);
    *aux_out = (float)NE * aux;
  }
}

// ================= FFN pipeline =================
// All FFN kernels decode expert = bid & 7 so (with round-robin block->XCD
// dispatch) every block of expert e lands on XCD e: per-XCD L2 working set =
// ONE expert's weights. (R3: FETCH 75.8 -> 17.4 MB, confirmed.)

// K1: u[slot,256] = bf16( gather(x) @ A1c )
__global__ __launch_bounds__(256) void k1_u(
    const float* __restrict__ x, const int* __restrict__ cnt,
    const int* __restrict__ perm, const u16* __restrict__ W1,
    u16* __restrict__ u) {
  __shared__ __align__(16) u16 As[8192], Bs[8192];
  __shared__ int tok_s[128];
  int bid = blockIdx.x;
  int e = bid & 7;
  int r0 = bid >> 3;
  int ntile = r0 & 1, mt = r0 >> 1;
  int m0 = mt << 7;
  int cntE = cnt[e];
  if (m0 >= cntE) return;
  int tid = threadIdx.x;
  if (tid < 128) {
    int mm = m0 + tid; if (mm > cntE - 1) mm = cntE - 1;
    tok_s[tid] = perm[e * T_TOK + mm];
  }
  __syncthreads();
  const u16* Bbase = W1 + (size_t)e * KR * DM + (size_t)(ntile * 128) * DM;
  int wv = tid >> 6, lane = tid & 63;
  int wm = wv >> 1, wn = wv & 1, ln = lane & 15, quad = lane >> 4;
  f32x4 acc[4][4];
#pragma unroll
  for (int a = 0; a < 4; a++)
#pragma unroll
    for (int b = 0; b < 4; b++) acc[a][b] = (f32x4){0.f, 0.f, 0.f, 0.f};
  for (int k0 = 0; k0 < DM; k0 += 64) {
    for (int i = tid; i < 2048; i += 256) {
      int row = i >> 4, c4 = i & 15;
      float4 v = *(const float4*)(x + (size_t)tok_s[row] * DM + k0 + c4 * 4);
      u16x4v o; o[0] = f2bf(v.x); o[1] = f2bf(v.y); o[2] = f2bf(v.z); o[3] = f2bf(v.w);
      *(u16x4v*)&As[row * 64 + ((c4 * 4) ^ ((row & 4) << 2))] = o;   // st_16x32 write
    }
    stage_tile(Bbase + k0, DM, Bs, tid);
    __syncthreads();
    mfma_block(As, Bs, acc, wm, wn, ln, quad);
    __syncthreads();
  }
  int slot0 = e * CAP + m0;
#pragma unroll
  for (int mt2 = 0; mt2 < 4; mt2++)
#pragma unroll
    for (int nt = 0; nt < 4; nt++)
#pragma unroll
      for (int r = 0; r < 4; r++) {
        int row = wm * 64 + mt2 * 16 + quad * 4 + r;
        int col = ntile * 128 + wn * 64 + nt * 16 + ln;
        u[(size_t)(slot0 + row) * KR + col] = f2bf(acc[mt2][nt][r]);
      }
}

// K23 v8: t[slot, 256] = gelu(u @ B1c) @ A2c — h never leaves LDS, t written once.
// v4-v7 were all pinned at ~2000 cyc per 64-row chunk-unit regardless of
// occupancy/tile/sync: bank-conflict throughput on every ds_read_b128 (my
// (row&7)<<3 swizzle left ~8 lanes/bank-quad, ~35 cyc/instr vs 12 clean).
// v8 = v7 structure + m201's st_16x32 swizzle (col ^= ((row>>2)&1)<<4),
// measured 141x conflict reduction on this exact read shape at 62% MfmaUtil.
// LDS: Us 64K (resident u tile) + Bs 2x16K + Hs 32K = 128 KB.
__global__ __launch_bounds__(512, 1) void k23(
    const u16* __restrict__ u, const int* __restrict__ cnt,
    const u16* __restrict__ V1, const u16* __restrict__ W2,
    u16* __restrict__ t) {
  __shared__ __align__(16) u16 Us[128 * 256];     // 64 KB, u tile resident (swizzled)
  __shared__ __align__(16) u16 Bs[2][128 * 64];   // 2x16 KB double-buffered weight chunks
  __shared__ __align__(16) u16 Hs[128 * 128];     // 32 KB gelu tile (swizzled)
  int bid = blockIdx.x;
  int e = bid & 7, mt = bid >> 3;
  int m0 = mt << 7;
  int cntE = cnt[e];
  if (m0 >= cntE) return;
  int tid = threadIdx.x;
  int slot0 = e * CAP + m0;
  const u16* ub  = u + (size_t)slot0 * KR;
  const u16* V1e = V1 + (size_t)e * DFF * KR;
  const u16* W2e = W2 + (size_t)e * KR * DFF;

  // ---- prologue: stage Us[128][256] (row = 512 B, source pre-swizzled) ----
#pragma unroll
  for (int r = 0; r < 8; r++) {
    int i = r * 512 + tid;                 // 16 B chunk id, 0..4095
    int row = i >> 5, cc = i & 31;
    gl_lds16(ub + (size_t)row * 256 + ((cc ^ (((row >> 2) & 1) << 1)) * 8), &Us[i * 8]);
  }
  stage_tile512(V1e + 0, KR, Bs[0], tid);  // chunk 0: f0=0, p=0
  __syncthreads();

  int wv = tid >> 6, lane = tid & 63;
  int wm = wv >> 2, wn = wv & 3;           // 2x4 wave grid
  int ln = lane & 15, quad = lane >> 4;
  int sw = (ln & 4) << 2;                  // st_16x32 read XOR (row&4 == ln&4)
  f32x4 tacc[4][4];   // [mt][hh*2+nt]; wave owns t rows wm*64+, cols hh*128+wn*32+
#pragma unroll
  for (int a = 0; a < 4; a++)
#pragma unroll
    for (int b = 0; b < 4; b++) tacc[a][b] = (f32x4){0.f, 0.f, 0.f, 0.f};
  f32x4 hacc[4][2];   // wave owns h rows wm*64+, cols wn*32+

  // chunk (f0i, p): p<4 -> phase A (h[128x128] += u @ V1 chunk k0=p),
  // p>=4 -> phase B (tacc[hh] += Hs @ W2 chunk, hh=(p>>1)&1, fi=p&1).
  // schedule: stage(c+1) first, ds_read c, MFMA, one __syncthreads.
  for (int f0i = 0; f0i < 16; f0i++) {
    int f0 = f0i << 7;
#pragma unroll
    for (int p = 0; p < 8; p++) {
      // ---- 1. issue next chunk's global_load_lds into the other buffer ----
      if (p < 3) {                          // pn=p+1 in {1,2,3}: V1, k0=pn
        stage_tile512(V1e + (size_t)f0 * KR + (p + 1) * 64, KR, Bs[(p + 1) & 1], tid);
      } else if (p < 7) {                   // pn in {4..7}: W2
        const int pn = p + 1;
        stage_tile512(W2e + (size_t)(((pn >> 1) & 1) * 128) * DFF + f0 + (pn & 1) * 64,
                      DFF, Bs[pn & 1], tid);
      } else {                              // pn wraps: next f0's V1 k0=0 (dummy at end)
        size_t f0n = (f0i == 15) ? (size_t)0 : (size_t)(f0 + 128);
        stage_tile512(V1e + f0n * KR, KR, Bs[0], tid);
      }
      // ---- 2+3. ds_read chunk c and MFMA ----
      const u16* curB = Bs[p & 1];
      if (p < 4) {
        if (p == 0) {
#pragma unroll
          for (int a = 0; a < 4; a++)
#pragma unroll
            for (int b = 0; b < 2; b++) hacc[a][b] = (f32x4){0.f, 0.f, 0.f, 0.f};
        }
#pragma unroll
        for (int ks = 0; ks < 2; ks++) {
          bf16x8 af[4], bf[2];
          int cu = (p * 64 + ks * 32 + quad * 8) ^ sw;
          int cb = (ks * 32 + quad * 8) ^ sw;
#pragma unroll
          for (int m = 0; m < 4; m++)
            af[m] = *(const bf16x8*)&Us[(wm * 64 + m * 16 + ln) * 256 + cu];
#pragma unroll
          for (int nt = 0; nt < 2; nt++)
            bf[nt] = *(const bf16x8*)&curB[(wn * 32 + nt * 16 + ln) * 64 + cb];
#pragma unroll
          for (int m = 0; m < 4; m++)
#pragma unroll
            for (int nt = 0; nt < 2; nt++)
              hacc[m][nt] = __builtin_amdgcn_mfma_f32_16x16x32_bf16(af[m], bf[nt], hacc[m][nt], 0, 0, 0);
        }
        if (p == 3) {
          // gelu -> Hs (st_16x32 write matches read)
#pragma unroll
          for (int m = 0; m < 4; m++)
#pragma unroll
            for (int nt = 0; nt < 2; nt++)
#pragma unroll
              for (int r = 0; r < 4; r++) {
                int row = wm * 64 + m * 16 + quad * 4 + r;
                int col = wn * 32 + nt * 16 + ln;
                float v = hacc[m][nt][r];
                float s = 1.f / (1.f + __expf(-1.702f * v));
                Hs[(row << 7) + (col ^ ((row & 4) << 2))] = f2bf(v * s);
              }
        }
      } else {
#pragma unroll
        for (int ks = 0; ks < 2; ks++) {
          bf16x8 af[4], bf[2];
          int ch = ((p & 1) * 64 + ks * 32 + quad * 8) ^ sw;
          int cb = (ks * 32 + quad * 8) ^ sw;
#pragma unroll
          for (int m = 0; m < 4; m++)
            af[m] = *(const bf16x8*)&Hs[((wm * 64 + m * 16 + ln) << 7) + ch];
#pragma unroll
          for (int nt = 0; nt < 2; nt++)
            bf[nt] = *(const bf16x8*)&curB[(wn * 32 + nt * 16 + ln) * 64 + cb];
#pragma unroll
          for (int m = 0; m < 4; m++)
#pragma unroll
            for (int nt = 0; nt < 2; nt++)
              tacc[m][((p >> 1) & 1) * 2 + nt] = __builtin_amdgcn_mfma_f32_16x16x32_bf16(af[m], bf[nt], tacc[m][((p >> 1) & 1) * 2 + nt], 0, 0, 0);
        }
      }
      // ---- 4. one barrier: drains stage(c+1) + publishes/protects Hs ----
      __syncthreads();
    }
  }
  // epilogue: t (bf16, written once — no RMW)
#pragma unroll
  for (int m = 0; m < 4; m++)
#pragma unroll
    for (int hh = 0; hh < 2; hh++)
#pragma unroll
      for (int nt = 0; nt < 2; nt++)
#pragma unroll
        for (int r = 0; r < 4; r++) {
          int row = wm * 64 + m * 16 + quad * 4 + r;
          int col = hh * 128 + wn * 32 + nt * 16 + ln;
          t[(size_t)(slot0 + row) * KR + col] = f2bf(tacc[m][hh * 2 + nt][r]);
        }
}

// K4: y[slot, 512] = gate * (t @ B2c)
__global__ __launch_bounds__(256) void k4_y(
    const u16* __restrict__ t, const int* __restrict__ cnt,
    const int* __restrict__ perm, const float* __restrict__ gate,
    const u16* __restrict__ V2, u16* __restrict__ y) {
  __shared__ __align__(16) u16 As[8192], Bs[8192];
  __shared__ float g_s[128];
  int bid = blockIdx.x;
  int e = bid & 7;
  int r0 = bid >> 3;
  int ntile = r0 & 3, mt = r0 >> 2;
  int m0 = mt << 7;
  int cntE = cnt[e];
  if (m0 >= cntE) return;
  int tid = threadIdx.x;
  if (tid < 128) {
    int mm = m0 + tid; if (mm > cntE - 1) mm = cntE - 1;
    int tk = perm[e * T_TOK + mm];
    g_s[tid] = gate[e * T_TOK + tk];
  }
  __syncthreads();
  int slot0 = e * CAP + m0;
  const u16* Abase = t + (size_t)slot0 * KR;
  const u16* Bbase = V2 + (size_t)e * DM * KR + (size_t)(ntile * 128) * KR;
  int wv = tid >> 6, lane = tid & 63;
  int wm = wv >> 1, wn = wv & 1, ln = lane & 15, quad = lane >> 4;
  f32x4 acc[4][4];
#pragma unroll
  for (int a = 0; a < 4; a++)
#pragma unroll
    for (int b = 0; b < 4; b++) acc[a][b] = (f32x4){0.f, 0.f, 0.f, 0.f};
  for (int k0 = 0; k0 < KR; k0 += 64) {
    stage_tile(Abase + k0, KR, As, tid);
    stage_tile(Bbase + k0, KR, Bs, tid);
    __syncthreads();
    mfma_block(As, Bs, acc, wm, wn, ln, quad);
    __syncthreads();
  }
#pragma unroll
  for (int mt2 = 0; mt2 < 4; mt2++)
#pragma unroll
    for (int nt = 0; nt < 4; nt++)
#pragma unroll
      for (int r = 0; r < 4; r++) {
        int row = wm * 64 + mt2 * 16 + quad * 4 + r;
        int col = ntile * 128 + wn * 64 + nt * 16 + ln;
        y[(size_t)(slot0 + row) * DM + col] = f2bf(acc[mt2][nt][r] * g_s[row]);
      }
}

// gather: out[t] = y[slotA] + y[slotB]
__global__ void gather_kernel(const u16* __restrict__ y, const int* __restrict__ slots,
                              float* __restrict__ out) {
  int idx = blockIdx.x * 256 + threadIdx.x;
  int t = idx >> 7, c4 = (idx & 127) * 4;
  int sA = slots[t * 2], sB = slots[t * 2 + 1];
  u16x4v a = *(const u16x4v*)&y[(size_t)sA * DM + c4];
  u16x4v b = *(const u16x4v*)&y[(size_t)sB * DM + c4];
  float4 o;
  o.x = bf2f(a[0]) + bf2f(b[0]);
  o.y = bf2f(a[1]) + bf2f(b[1]);
  o.z = bf2f(a[2]) + bf2f(b[2]);
  o.w = bf2f(a[3]) + bf2f(b[3]);
  *(float4*)&out[(size_t)t * DM + c4] = o;
}

// ---------------- launch ----------------
extern "C" void kernel_launch(void* const* d_in, const int* in_sizes, int n_in,
                              void* d_out, int out_size, void* d_ws, size_t ws_size,
                              hipStream_t stream) {
  const float* x   = (const float*)d_in[0];
  const float* Wr  = (const float*)d_in[1];
  const float* fc1 = (const float*)d_in[2];
  const float* fc2 = (const float*)d_in[3];
  const float* A1  = (const float*)d_in[4];
  const float* B1  = (const float*)d_in[5];
  const float* A2  = (const float*)d_in[6];
  const float* B2  = (const float*)d_in[7];
  float* out = (float*)d_out;

  char* ws = (char*)d_ws;
  float* sw1     = (float*)(ws + 0);
  int*   idx1    = (int*)(ws + 512);
  float* sw2     = (float*)(ws + 1024);
  int*   idx2    = (int*)(ws + 1536);
  int*   cnt     = (int*)(ws + 2048);
  float* probsum = (float*)(ws + 2560);
  int*   eidx    = (int*)(ws + 8192);                      // 64 KB
  int*   slots   = (int*)(ws + 8192 + 65536);              // 128 KB
  float* gate    = (float*)(ws + 8192 + 65536 + 131072);   // 512 KB
  int*   perm    = (int*)(ws + 8192 + 65536 + 131072 + 524288); // 512 KB
  u16*   W1      = (u16*)(ws + 8192 + 65536 + 131072 + 2 * 524288);
  u16*   V1      = W1 + 1048576;
  u16*   W2      = V1 + 4194304;
  u16*   V2      = W2 + 4194304;
  char*  endW    = (char*)(V2 + 1048576);                    // ~22.2 MB
  u16*   u_buf   = (u16*)endW;                               // 49152x256 bf16 = 25.2 MB
  u16*   t_buf   = (u16*)(endW + 25165824);                  // 49152x256 bf16 = 25.2 MB
  u16*   y_buf   = (u16*)(endW + 2 * 25165824);              // 49152x512 bf16 = 50.3 MB
  // total ws use ≈ 123 MB

  zero_kernel<<<3, 256, 0, stream>>>(cnt, probsum);
  compose_meta<<<1, 64, 0, stream>>>(fc1, fc2, sw1, idx1, sw2, idx2);
  build_AT<<<32 * (DM / 64), 256, 0, stream>>>(A1, idx1, sw1, W1, DM);
  build_AT<<<32 * (DFF / 64), 256, 0, stream>>>(A2, idx2, sw2, W2, DFF);
  build_V<<<20480, 256, 0, stream>>>(B1, B2, sw1, idx1, sw2, idx2, V1, V2);
  router_kernel<<<T_TOK / 64, 256, 0, stream>>>(x, Wr, probsum, eidx, gate);
  scatter_kernel<<<T_TOK / 256, 256, 0, stream>>>(eidx, cnt, perm, slots);
  aux_kernel<<<1, 64, 0, stream>>>(cnt, probsum, out + (out_size - 1));

  k1_u<<<2 * NE * MT_E, 256, 0, stream>>>(x, cnt, perm, W1, u_buf);
  k23<<<NE * (CAP / 128), 512, 0, stream>>>(u_buf, cnt, V1, W2, t_buf);
  k4_y<<<4 * NE * MT_E, 256, 0, stream>>>(t_buf, cnt, perm, gate, V2, y_buf);
  gather_kernel<<<T_TOK * DM / 4 / 256, 256, 0, stream>>>(y_buf, slots, out);
}

// Round 7
// 441.356 us; speedup vs baseline: 1.0772x; 1.0772x over previous
//
#include <hip/hip_runtime.h>

// ---------------- problem constants ----------------
#define T_TOK 16384
#define DM    512
#define DFF   2048
#define NE    8
#define NP    16
#define KP    4
#define RANK  64
#define KR    256           // KP * RANK
#define EPSF  1e-8f
#define CAP   6144          // per-expert pair capacity (expected ~4096)
#define MT_E  48            // CAP / 128 M-tiles per expert

typedef unsigned short u16;
typedef __bf16 bf16x8 __attribute__((ext_vector_type(8)));
typedef float  f32x4  __attribute__((ext_vector_type(4)));
typedef unsigned short u16x8v __attribute__((ext_vector_type(8)));
typedef unsigned short u16x4v __attribute__((ext_vector_type(4)));

typedef __attribute__((address_space(3))) void as3_void;
typedef __attribute__((address_space(1))) void as1_void;

// native RTNE f32->bf16 (compiler emits v_cvt_pk_bf16_f32 pairs; ~4x fewer
// VALU ops than the manual round-and-shift used through R6)
__device__ __forceinline__ u16 f2bf(float f) {
  return __builtin_bit_cast(u16, (__bf16)f);
}
__device__ __forceinline__ float bf2f(u16 v) {
  unsigned int u = ((unsigned int)v) << 16;
  return __builtin_bit_cast(float, u);
}

__device__ __forceinline__ void gl_lds16(const u16* g, u16* l) {
  __builtin_amdgcn_global_load_lds((as1_void*)g, (as3_void*)l, 16, 0, 0);
}

// ---- 3-bit XOR swizzle for 64-col (128 B row-stride) LDS tiles ----
// granule' = granule ^ (row&7): every consecutive-8-lane group of a
// ds_read_b128 spreads across all 8 16B-granules -> ~conflict-free.
// (R6 lesson: m201's st_16x32 1-bit XOR maps WRONG onto this layout —
// 4 lanes/granule, 3.5x the conflicts. R6 also showed conflicts are only
// ~6% of k23 time; kernel is latency-bound -> v4 2-blocks/CU TLP optimum.)

// stage 128x64 bf16 tile into LDS, source pre-swizzled (gl_lds dst linear)
__device__ __forceinline__ void stage_tile(const u16* g, int ld, u16* lds_tile, int tid) {
  int row = tid >> 3, cc = tid & 7;
#pragma unroll
  for (int ri = 0; ri < 4; ri++) {
    int rg = ri * 32 + row;
    gl_lds16(g + (size_t)rg * ld + ((cc ^ (rg & 7)) * 8), &lds_tile[rg * 64 + cc * 8]);
  }
}

// shared 128x128 MFMA inner step over one BK=64 LDS tile pair (256-thr kernels)
__device__ __forceinline__ void mfma_block(const u16* As, const u16* Bs, f32x4 acc[4][4],
                                           int wm, int wn, int ln, int quad) {
  int sw = (ln & 7) << 3;
#pragma unroll
  for (int ks = 0; ks < 2; ks++) {
    bf16x8 af[4], bf[4];
    int co = (ks * 32 + quad * 8) ^ sw;
#pragma unroll
    for (int mt = 0; mt < 4; mt++)
      af[mt] = *(const bf16x8*)&As[(wm * 64 + mt * 16 + ln) * 64 + co];
#pragma unroll
    for (int nt = 0; nt < 4; nt++)
      bf[nt] = *(const bf16x8*)&Bs[(wn * 64 + nt * 16 + ln) * 64 + co];
    __builtin_amdgcn_s_setprio(1);
#pragma unroll
    for (int mt = 0; mt < 4; mt++)
#pragma unroll
      for (int nt = 0; nt < 4; nt++)
        acc[mt][nt] = __builtin_amdgcn_mfma_f32_16x16x32_bf16(af[mt], bf[nt], acc[mt][nt], 0, 0, 0);
    __builtin_amdgcn_s_setprio(0);
  }
}

// ---------------- zero counters ----------------
__global__ void zero_kernel(int* __restrict__ cnt, float* __restrict__ probsum) {
  int i = blockIdx.x * 256 + threadIdx.x;
  if (i < NE) cnt[i] = 0;
  if (i >= NE && i < NE + NE * 64) probsum[i - NE] = 0.f;
}

// ---------------- primitive-bank softmax + top-4 ----------------
__global__ void compose_meta(const float* __restrict__ fc1, const float* __restrict__ fc2,
                             float* __restrict__ sw1, int* __restrict__ idx1,
                             float* __restrict__ sw2, int* __restrict__ idx2) {
  int tid = threadIdx.x;
  if (tid >= 16) return;
  const float* src = (tid < 8) ? fc1 : fc2;
  float* sw = (tid < 8) ? sw1 : sw2;
  int*  idx = (tid < 8) ? idx1 : idx2;
  int e = tid & 7;
  float wv[NP];
  float mx = -1e30f;
  for (int p = 0; p < NP; p++) { wv[p] = src[e * NP + p]; mx = fmaxf(mx, wv[p]); }
  float sum = 0.f;
  for (int p = 0; p < NP; p++) { wv[p] = __expf(wv[p] - mx); sum += wv[p]; }
  float inv = 1.f / sum;
  for (int p = 0; p < NP; p++) wv[p] *= inv;
  float tw[KP]; int ti[KP];
  for (int k = 0; k < KP; k++) {
    int best = 0; float bv = -1.f;
    for (int p = 0; p < NP; p++) if (wv[p] > bv) { bv = wv[p]; best = p; }
    tw[k] = bv; ti[k] = best; wv[best] = -2.f;
  }
  float ts = tw[0] + tw[1] + tw[2] + tw[3];
  float invt = 1.f / (ts + EPSF);
  for (int k = 0; k < KP; k++) {
    sw[e * KP + k] = sqrtf(tw[k] * invt + EPSF);
    idx[e * KP + k] = ti[k];
  }
}

// ---------------- build W1/W2 via LDS transpose ----------------
__global__ __launch_bounds__(256) void build_AT(
    const float* __restrict__ A, const int* __restrict__ idx,
    const float* __restrict__ sw, u16* __restrict__ W, int D) {
  __shared__ u16 T[64 * 68];
  int ntile = D >> 6;
  int dt = blockIdx.x % ntile;
  int g  = blockIdx.x / ntile;      // e*4+k
  int p = idx[g]; float s = sw[g];
  int d0 = dt * 64;
  int tid = threadIdx.x;
  {
    int rr = (tid & 15) * 4, dd = tid >> 4;
#pragma unroll
    for (int pass = 0; pass < 4; pass++) {
      int d = pass * 16 + dd;
      float4 v = *(const float4*)(A + ((size_t)p * D + d0 + d) * 64 + rr);
      T[(rr + 0) * 68 + d] = f2bf(v.x * s);
      T[(rr + 1) * 68 + d] = f2bf(v.y * s);
      T[(rr + 2) * 68 + d] = f2bf(v.z * s);
      T[(rr + 3) * 68 + d] = f2bf(v.w * s);
    }
  }
  __syncthreads();
  int e = g >> 2, k = g & 3;
  int c = (tid & 15) * 4, r = tid >> 4;
#pragma unroll
  for (int pass = 0; pass < 4; pass++) {
    int rr = pass * 16 + r;
    u16x4v o;
#pragma unroll
    for (int j = 0; j < 4; j++) o[j] = T[rr * 68 + c + j];
    *(u16x4v*)&W[((size_t)e * KR + k * 64 + rr) * D + d0 + c] = o;
  }
}

// ---------------- build V1/V2 ----------------
__global__ void build_V(const float* __restrict__ B1, const float* __restrict__ B2,
                        const float* __restrict__ sw1, const int* __restrict__ idx1,
                        const float* __restrict__ sw2, const int* __restrict__ idx2,
                        u16* __restrict__ V1, u16* __restrict__ V2) {
  const int S2 = NE * DFF * KR;   // V1[e][f][kr] = B1[p][r][f]*s
  const int S4 = NE * DM * KR;    // V2[e][d][kr] = B2[p][r][d]*s
  int i = blockIdx.x * 256 + threadIdx.x;
  if (i < S2) {
    int kr = i & 255; int f = (i >> 8) & 2047; int e = i >> 19;
    int k = kr >> 6, r = kr & 63; int p = idx1[e * 4 + k];
    V1[i] = f2bf(B1[((size_t)p * RANK + r) * DFF + f] * sw1[e * 4 + k]);
  } else if (i < S2 + S4) {
    int j = i - S2;
    int kr = j & 255; int d = (j >> 8) & 511; int e = j >> 17;
    int k = kr >> 6, r = kr & 63; int p = idx2[e * 4 + k];
    V2[j] = f2bf(B2[((size_t)p * RANK + r) * DM + d] * sw2[e * 4 + k]);
  }
}

// ---------------- router, token-per-lane (k-split 4) ----------------
__global__ __launch_bounds__(256) void router_kernel(
    const float* __restrict__ x, const float* __restrict__ Wr,
    float* __restrict__ probsum, int* __restrict__ eidx,
    float* __restrict__ gate) {
  __shared__ float wr_s[NE * 4 * 132];
  __shared__ float ps_s[NE];
  int tid = threadIdx.x;
  if (tid < NE) ps_s[tid] = 0.f;
  for (int i = tid; i < NE * DM; i += 256) {
    int e = i >> 9, k = i & 511;
    wr_s[(e * 4 + (k >> 7)) * 132 + (k & 127)] = Wr[i];
  }
  __syncthreads();
  int lane = tid & 63, wv = tid >> 6;
  int tl = lane & 15, sl = lane >> 4;
  int t = blockIdx.x * 64 + wv * 16 + tl;
  const float* xp = x + (size_t)t * DM + sl * 128;
  const float* wp = &wr_s[sl * 132];
  float acc[NE];
#pragma unroll
  for (int e = 0; e < NE; e++) acc[e] = 0.f;
  for (int c = 0; c < 32; c++) {
    float4 xv = *(const float4*)(xp + c * 4);
#pragma unroll
    for (int e = 0; e < NE; e++) {
      float4 w4 = *(const float4*)(wp + e * 4 * 132 + c * 4);
      acc[e] += xv.x * w4.x + xv.y * w4.y + xv.z * w4.z + xv.w * w4.w;
    }
  }
#pragma unroll
  for (int e = 0; e < NE; e++) {
    acc[e] += __shfl_xor(acc[e], 16, 64);
    acc[e] += __shfl_xor(acc[e], 32, 64);
  }
  if (sl == 0) {
    float mx = acc[0];
#pragma unroll
    for (int e = 1; e < NE; e++) mx = fmaxf(mx, acc[e]);
    float pe[NE]; float sum = 0.f;
#pragma unroll
    for (int e = 0; e < NE; e++) { pe[e] = __expf(acc[e] - mx); sum += pe[e]; }
    float inv = 1.f / sum;
#pragma unroll
    for (int e = 0; e < NE; e++) pe[e] *= inv;
    int i0 = 0;
#pragma unroll
    for (int e = 1; e < NE; e++) if (pe[e] > pe[i0]) i0 = e;
    int i1 = (i0 == 0) ? 1 : 0;
#pragma unroll
    for (int e = 0; e < NE; e++) if (e != i0 && pe[e] > pe[i1]) i1 = e;
    float p0 = pe[i0], p1 = pe[i1];
    float gd = 1.f / (p0 + p1 + EPSF);
    eidx[t] = i0 | (i1 << 3);
    gate[i0 * T_TOK + t] = p0 * gd;
    gate[i1 * T_TOK + t] = p1 * gd;
#pragma unroll
    for (int e = 0; e < NE; e++) atomicAdd(&ps_s[e], pe[e]);
  }
  __syncthreads();
  if (tid < NE) atomicAdd(&probsum[tid * 64 + (blockIdx.x & 63)], ps_s[tid]);
}

// ---------------- scatter (block-aggregated cnt) + per-token slot pairs ----------
__global__ void scatter_kernel(const int* __restrict__ eidx,
                               int* __restrict__ cnt, int* __restrict__ perm,
                               int* __restrict__ slots) {
  __shared__ int hist[NE], base[NE];
  int tid = threadIdx.x;
  if (tid < NE) hist[tid] = 0;
  __syncthreads();
  int t = blockIdx.x * 256 + tid;
  int pk = eidx[t];
  int e0 = pk & 7, e1 = (pk >> 3) & 7;
  int p0 = atomicAdd(&hist[e0], 1);
  int p1 = atomicAdd(&hist[e1], 1);
  __syncthreads();
  if (tid < NE) base[tid] = atomicAdd(&cnt[tid], hist[tid]);
  __syncthreads();
  int g0 = base[e0] + p0; if (g0 >= CAP) g0 = CAP - 1;
  int g1 = base[e1] + p1; if (g1 >= CAP) g1 = CAP - 1;
  perm[e0 * T_TOK + g0] = t;
  perm[e1 * T_TOK + g1] = t;
  slots[t * 2]     = e0 * CAP + g0;
  slots[t * 2 + 1] = e1 * CAP + g1;
}

// ---------------- aux loss (one wave) ----------------
__global__ void aux_kernel(const int* __restrict__ cnt, const float* __restrict__ probsum,
                           float* __restrict__ aux_out) {
  int lane = threadIdx.x;
  if (lane >= 64) return;
  float s[NE];
#pragma unroll
  for (int e = 0; e < NE; e++) {
    float v = probsum[e * 64 + lane];
#pragma unroll
    for (int off = 32; off > 0; off >>= 1) v += __shfl_xor(v, off, 64);
    s[e] = v;
  }
  if (lane == 0) {
    float c[NE]; float cs = 0.f;
    for (int e = 0; e < NE; e++) { c[e] = (float)cnt[e]; cs += c[e]; }
    float aux = 0.f;
    for (int e = 0; e < NE; e++)
      aux += (c[e] / (cs + EPSF)) * (s[e] / (float)T_TOK);
    *aux_out = (float)NE * aux;
  }
}

// ================= FFN pipeline =================
// All FFN kernels decode expert = bid & 7 so (with round-robin block->XCD
// dispatch) every block of expert e lands on XCD e: per-XCD L2 working set =
// ONE expert's weights. (R3: FETCH 75.8 -> 17.4 MB, confirmed.)

// K1: u[slot,256] = bf16( gather(x) @ A1c )
__global__ __launch_bounds__(256) void k1_u(
    const float* __restrict__ x, const int* __restrict__ cnt,
    const int* __restrict__ perm, const u16* __restrict__ W1,
    u16* __restrict__ u) {
  __shared__ __align__(16) u16 As[8192], Bs[8192];
  __shared__ int tok_s[128];
  int bid = blockIdx.x;
  int e = bid & 7;
  int r0 = bid >> 3;
  int ntile = r0 & 1, mt = r0 >> 1;
  int m0 = mt << 7;
  int cntE = cnt[e];
  if (m0 >= cntE) return;
  int tid = threadIdx.x;
  if (tid < 128) {
    int mm = m0 + tid; if (mm > cntE - 1) mm = cntE - 1;
    tok_s[tid] = perm[e * T_TOK + mm];
  }
  __syncthreads();
  const u16* Bbase = W1 + (size_t)e * KR * DM + (size_t)(ntile * 128) * DM;
  int wv = tid >> 6, lane = tid & 63;
  int wm = wv >> 1, wn = wv & 1, ln = lane & 15, quad = lane >> 4;
  f32x4 acc[4][4];
#pragma unroll
  for (int a = 0; a < 4; a++)
#pragma unroll
    for (int b = 0; b < 4; b++) acc[a][b] = (f32x4){0.f, 0.f, 0.f, 0.f};
  for (int k0 = 0; k0 < DM; k0 += 64) {
    for (int i = tid; i < 2048; i += 256) {
      int row = i >> 4, c4 = i & 15;
      float4 v = *(const float4*)(x + (size_t)tok_s[row] * DM + k0 + c4 * 4);
      u16x4v o; o[0] = f2bf(v.x); o[1] = f2bf(v.y); o[2] = f2bf(v.z); o[3] = f2bf(v.w);
      *(u16x4v*)&As[row * 64 + ((c4 * 4) ^ ((row & 7) << 3))] = o;   // swizzled write
    }
    stage_tile(Bbase + k0, DM, Bs, tid);
    __syncthreads();
    mfma_block(As, Bs, acc, wm, wn, ln, quad);
    __syncthreads();
  }
  int slot0 = e * CAP + m0;
#pragma unroll
  for (int mt2 = 0; mt2 < 4; mt2++)
#pragma unroll
    for (int nt = 0; nt < 4; nt++)
#pragma unroll
      for (int r = 0; r < 4; r++) {
        int row = wm * 64 + mt2 * 16 + quad * 4 + r;
        int col = ntile * 128 + wn * 64 + nt * 16 + ln;
        u[(size_t)(slot0 + row) * KR + col] = f2bf(acc[mt2][nt][r]);
      }
}

// K23 v9: t[slot, 256] = gelu(u @ B1c) @ A2c — h never leaves LDS, t written once.
// Empirical record: v4 (M=64, 80 KB, 2 blocks/CU, drain barrier, 3-bit swz)
// = 208 us is the optimum; counted-vmcnt (v5), M=128 (v6), 8 waves (v7),
// st_16x32 (v8) all lost or tied. Kernel is latency-bound (LDS ~40%, VALU
// ~20%, MFMA ~13%, conflicts ~6%); 2 independent blocks/CU = best TLP.
// v9 = v4 + s_setprio(1) around MFMA clusters (T5, pays with unsynced
// blocks) + native bf16 cvt in gelu/epilogue (VALU trim).
// LDS: Us 32K + Bs 2x16K + Hs 16K = 80 KB -> 2 blocks/CU.
__global__ __launch_bounds__(256, 2) void k23(
    const u16* __restrict__ u, const int* __restrict__ cnt,
    const u16* __restrict__ V1, const u16* __restrict__ W2,
    u16* __restrict__ t) {
  __shared__ __align__(16) u16 Us[64 * 256];      // 32 KB, u tile resident (swizzled)
  __shared__ __align__(16) u16 Bs[2][128 * 64];   // 2x16 KB double-buffered weight chunks
  __shared__ __align__(16) u16 Hs[64 * 128];      // 16 KB gelu tile (swizzled)
  int bid = blockIdx.x;
  int e = bid & 7, mt = bid >> 3;
  int m0 = mt << 6;
  int cntE = cnt[e];
  if (m0 >= cntE) return;
  int tid = threadIdx.x;
  int slot0 = e * CAP + m0;
  const u16* ub  = u + (size_t)slot0 * KR;
  const u16* V1e = V1 + (size_t)e * DFF * KR;
  const u16* W2e = W2 + (size_t)e * KR * DFF;

  // ---- prologue: stage Us (source pre-swizzled per 512 B row) + chunk 0 ----
#pragma unroll
  for (int r = 0; r < 8; r++) {
    int i = r * 256 + tid;                 // 16 B chunk id, 0..2047
    int row = i >> 5, cc = i & 31;
    gl_lds16(ub + (size_t)row * 256 + ((cc ^ (row & 7)) * 8), &Us[i * 8]);
  }
  stage_tile(V1e + 0, KR, Bs[0], tid);     // chunk 0: f0=0, p=0
  __syncthreads();

  int wv = tid >> 6, lane = tid & 63;
  int ln = lane & 15, quad = lane >> 4;
  int sw = (ln & 7) << 3;
  f32x4 tacc[4][4];   // [m][hh*2+nt] ; wave wv owns t cols hh*128 + wv*32 + nt*16 + ln
#pragma unroll
  for (int a = 0; a < 4; a++)
#pragma unroll
    for (int b = 0; b < 4; b++) tacc[a][b] = (f32x4){0.f, 0.f, 0.f, 0.f};
  f32x4 hacc[4][2];

  // chunk (f0i, p): p<4 -> phase A (h += u @ V1 chunk k0=p), p>=4 -> phase B
  // (tacc[hh] += Hs @ W2 chunk hh=(p>>1)&1, fi=p&1). Bs buffer index = p&1.
  for (int f0i = 0; f0i < 16; f0i++) {
    int f0 = f0i << 7;
#pragma unroll
    for (int p = 0; p < 8; p++) {
      // ---- 1. issue next chunk's global_load_lds into the other buffer ----
      {
        const int pn = (p + 1) & 7;            // compile-time
        if (p != 7) {
          const u16* src; int ld;
          if (pn < 4) { src = V1e + (size_t)f0 * KR + pn * 64; ld = KR; }
          else { src = W2e + (size_t)(((pn >> 1) & 1) * 128) * DFF + f0 + (pn & 1) * 64; ld = DFF; }
          stage_tile(src, ld, Bs[pn & 1], tid);
        } else if (f0i != 15) {
          stage_tile(V1e + (size_t)(f0 + 128) * KR, KR, Bs[0], tid);  // next f0, chunk p=0
        }
      }
      // ---- 2. ds_reads for chunk (f0i,p) — all indices compile-time ----
      bf16x8 af[2][4], bf[2][2];
      const u16* curB = Bs[p & 1];
#pragma unroll
      for (int ks = 0; ks < 2; ks++) {
        int cb = (ks * 32 + quad * 8) ^ sw;
#pragma unroll
        for (int nt = 0; nt < 2; nt++)
          bf[ks][nt] = *(const bf16x8*)&curB[(wv * 32 + nt * 16 + ln) * 64 + cb];
#pragma unroll
        for (int m = 0; m < 4; m++) {
          if (p < 4) {
            int cu = (p * 64 + ks * 32 + quad * 8) ^ sw;
            af[ks][m] = *(const bf16x8*)&Us[(m * 16 + ln) * 256 + cu];
          } else {
            int ch = ((p & 1) * 64 + ks * 32 + quad * 8) ^ sw;
            af[ks][m] = *(const bf16x8*)&Hs[((m * 16 + ln) << 7) + ch];
          }
        }
      }
      // ---- 3. MFMA on chunk (covers in-flight loads' latency) ----
      if (p < 4) {
        if (p == 0) {
#pragma unroll
          for (int a = 0; a < 4; a++)
#pragma unroll
            for (int b = 0; b < 2; b++) hacc[a][b] = (f32x4){0.f, 0.f, 0.f, 0.f};
        }
        __builtin_amdgcn_s_setprio(1);
#pragma unroll
        for (int ks = 0; ks < 2; ks++)
#pragma unroll
          for (int m = 0; m < 4; m++)
#pragma unroll
            for (int nt = 0; nt < 2; nt++)
              hacc[m][nt] = __builtin_amdgcn_mfma_f32_16x16x32_bf16(af[ks][m], bf[ks][nt], hacc[m][nt], 0, 0, 0);
        __builtin_amdgcn_s_setprio(0);
        if (p == 3) {
          // gelu -> Hs (swizzled write matches swizzled read)
#pragma unroll
          for (int m = 0; m < 4; m++)
#pragma unroll
            for (int nt = 0; nt < 2; nt++)
#pragma unroll
              for (int r = 0; r < 4; r++) {
                int row = m * 16 + quad * 4 + r;
                int col = wv * 32 + nt * 16 + ln;
                float v = hacc[m][nt][r];
                float s = 1.f / (1.f + __expf(-1.702f * v));
                Hs[(row << 7) + (col ^ ((row & 7) << 3))] = f2bf(v * s);
              }
        }
      } else {
        __builtin_amdgcn_s_setprio(1);
#pragma unroll
        for (int ks = 0; ks < 2; ks++)
#pragma unroll
          for (int m = 0; m < 4; m++)
#pragma unroll
            for (int nt = 0; nt < 2; nt++)
              tacc[m][((p >> 1) & 1) * 2 + nt] = __builtin_amdgcn_mfma_f32_16x16x32_bf16(af[ks][m], bf[ks][nt], tacc[m][((p >> 1) & 1) * 2 + nt], 0, 0, 0);
        __builtin_amdgcn_s_setprio(0);
      }
      // ---- 4. one barrier: drains vmcnt for next chunk's loads + publishes Hs ----
      __syncthreads();
    }
  }
  // epilogue: t (bf16, written once — no RMW)
#pragma unroll
  for (int m = 0; m < 4; m++)
#pragma unroll
    for (int hh = 0; hh < 2; hh++)
#pragma unroll
      for (int nt = 0; nt < 2; nt++)
#pragma unroll
        for (int r = 0; r < 4; r++) {
          int row = m * 16 + quad * 4 + r;
          int col = hh * 128 + wv * 32 + nt * 16 + ln;
          t[(size_t)(slot0 + row) * KR + col] = f2bf(tacc[m][hh * 2 + nt][r]);
        }
}

// K4: y[slot, 512] = gate * (t @ B2c)
__global__ __launch_bounds__(256) void k4_y(
    const u16* __restrict__ t, const int* __restrict__ cnt,
    const int* __restrict__ perm, const float* __restrict__ gate,
    const u16* __restrict__ V2, u16* __restrict__ y) {
  __shared__ __align__(16) u16 As[8192], Bs[8192];
  __shared__ float g_s[128];
  int bid = blockIdx.x;
  int e = bid & 7;
  int r0 = bid >> 3;
  int ntile = r0 & 3, mt = r0 >> 2;
  int m0 = mt << 7;
  int cntE = cnt[e];
  if (m0 >= cntE) return;
  int tid = threadIdx.x;
  if (tid < 128) {
    int mm = m0 + tid; if (mm > cntE - 1) mm = cntE - 1;
    int tk = perm[e * T_TOK + mm];
    g_s[tid] = gate[e * T_TOK + tk];
  }
  __syncthreads();
  int slot0 = e * CAP + m0;
  const u16* Abase = t + (size_t)slot0 * KR;
  const u16* Bbase = V2 + (size_t)e * DM * KR + (size_t)(ntile * 128) * KR;
  int wv = tid >> 6, lane = tid & 63;
  int wm = wv >> 1, wn = wv & 1, ln = lane & 15, quad = lane >> 4;
  f32x4 acc[4][4];
#pragma unroll
  for (int a = 0; a < 4; a++)
#pragma unroll
    for (int b = 0; b < 4; b++) acc[a][b] = (f32x4){0.f, 0.f, 0.f, 0.f};
  for (int k0 = 0; k0 < KR; k0 += 64) {
    stage_tile(Abase + k0, KR, As, tid);
    stage_tile(Bbase + k0, KR, Bs, tid);
    __syncthreads();
    mfma_block(As, Bs, acc, wm, wn, ln, quad);
    __syncthreads();
  }
#pragma unroll
  for (int mt2 = 0; mt2 < 4; mt2++)
#pragma unroll
    for (int nt = 0; nt < 4; nt++)
#pragma unroll
      for (int r = 0; r < 4; r++) {
        int row = wm * 64 + mt2 * 16 + quad * 4 + r;
        int col = ntile * 128 + wn * 64 + nt * 16 + ln;
        y[(size_t)(slot0 + row) * DM + col] = f2bf(acc[mt2][nt][r] * g_s[row]);
      }
}

// gather: out[t] = y[slotA] + y[slotB]
__global__ void gather_kernel(const u16* __restrict__ y, const int* __restrict__ slots,
                              float* __restrict__ out) {
  int idx = blockIdx.x * 256 + threadIdx.x;
  int t = idx >> 7, c4 = (idx & 127) * 4;
  int sA = slots[t * 2], sB = slots[t * 2 + 1];
  u16x4v a = *(const u16x4v*)&y[(size_t)sA * DM + c4];
  u16x4v b = *(const u16x4v*)&y[(size_t)sB * DM + c4];
  float4 o;
  o.x = bf2f(a[0]) + bf2f(b[0]);
  o.y = bf2f(a[1]) + bf2f(b[1]);
  o.z = bf2f(a[2]) + bf2f(b[2]);
  o.w = bf2f(a[3]) + bf2f(b[3]);
  *(float4*)&out[(size_t)t * DM + c4] = o;
}

// ---------------- launch ----------------
extern "C" void kernel_launch(void* const* d_in, const int* in_sizes, int n_in,
                              void* d_out, int out_size, void* d_ws, size_t ws_size,
                              hipStream_t stream) {
  const float* x   = (const float*)d_in[0];
  const float* Wr  = (const float*)d_in[1];
  const float* fc1 = (const float*)d_in[2];
  const float* fc2 = (const float*)d_in[3];
  const float* A1  = (const float*)d_in[4];
  const float* B1  = (const float*)d_in[5];
  const float* A2  = (const float*)d_in[6];
  const float* B2  = (const float*)d_in[7];
  float* out = (float*)d_out;

  char* ws = (char*)d_ws;
  float* sw1     = (float*)(ws + 0);
  int*   idx1    = (int*)(ws + 512);
  float* sw2     = (float*)(ws + 1024);
  int*   idx2    = (int*)(ws + 1536);
  int*   cnt     = (int*)(ws + 2048);
  float* probsum = (float*)(ws + 2560);
  int*   eidx    = (int*)(ws + 8192);                      // 64 KB
  int*   slots   = (int*)(ws + 8192 + 65536);              // 128 KB
  float* gate    = (float*)(ws + 8192 + 65536 + 131072);   // 512 KB
  int*   perm    = (int*)(ws + 8192 + 65536 + 131072 + 524288); // 512 KB
  u16*   W1      = (u16*)(ws + 8192 + 65536 + 131072 + 2 * 524288);
  u16*   V1      = W1 + 1048576;
  u16*   W2      = V1 + 4194304;
  u16*   V2      = W2 + 4194304;
  char*  endW    = (char*)(V2 + 1048576);                    // ~22.2 MB
  u16*   u_buf   = (u16*)endW;                               // 49152x256 bf16 = 25.2 MB
  u16*   t_buf   = (u16*)(endW + 25165824);                  // 49152x256 bf16 = 25.2 MB
  u16*   y_buf   = (u16*)(endW + 2 * 25165824);              // 49152x512 bf16 = 50.3 MB
  // total ws use ≈ 123 MB

  zero_kernel<<<3, 256, 0, stream>>>(cnt, probsum);
  compose_meta<<<1, 64, 0, stream>>>(fc1, fc2, sw1, idx1, sw2, idx2);
  build_AT<<<32 * (DM / 64), 256, 0, stream>>>(A1, idx1, sw1, W1, DM);
  build_AT<<<32 * (DFF / 64), 256, 0, stream>>>(A2, idx2, sw2, W2, DFF);
  build_V<<<20480, 256, 0, stream>>>(B1, B2, sw1, idx1, sw2, idx2, V1, V2);
  router_kernel<<<T_TOK / 64, 256, 0, stream>>>(x, Wr, probsum, eidx, gate);
  scatter_kernel<<<T_TOK / 256, 256, 0, stream>>>(eidx, cnt, perm, slots);
  aux_kernel<<<1, 64, 0, stream>>>(cnt, probsum, out + (out_size - 1));

  k1_u<<<2 * NE * MT_E, 256, 0, stream>>>(x, cnt, perm, W1, u_buf);
  k23<<<NE * (CAP / 64), 256, 0, stream>>>(u_buf, cnt, V1, W2, t_buf);
  k4_y<<<4 * NE * MT_E, 256, 0, stream>>>(t_buf, cnt, perm, gate, V2, y_buf);
  gather_kernel<<<T_TOK * DM / 4 / 256, 256, 0, stream>>>(y_buf, slots, out);
}

// Round 8
// 360.063 us; speedup vs baseline: 1.3204x; 1.2258x over previous
//
#include <hip/hip_runtime.h>

// ---------------- problem constants ----------------
#define T_TOK 16384
#define DM    512
#define DFF   2048
#define NE    8
#define NP    16
#define KP    4
#define RANK  64
#define KR    256           // KP * RANK
#define EPSF  1e-8f
#define CAP   6144          // per-expert pair capacity (expected ~4096)
#define MT_E  48            // CAP / 128 M-tiles per expert

typedef unsigned short u16;
typedef __bf16 bf16x8 __attribute__((ext_vector_type(8)));
typedef float  f32x4  __attribute__((ext_vector_type(4)));
typedef unsigned short u16x8v __attribute__((ext_vector_type(8)));
typedef unsigned short u16x4v __attribute__((ext_vector_type(4)));

typedef __attribute__((address_space(3))) void as3_void;
typedef __attribute__((address_space(1))) void as1_void;

__device__ __forceinline__ u16 f2bf(float f) {
  return __builtin_bit_cast(u16, (__bf16)f);    // native RTNE cvt (R7)
}
__device__ __forceinline__ float bf2f(u16 v) {
  unsigned int u = ((unsigned int)v) << 16;
  return __builtin_bit_cast(float, u);
}

__device__ __forceinline__ void gl_lds16(const u16* g, u16* l) {
  __builtin_amdgcn_global_load_lds((as1_void*)g, (as3_void*)l, 16, 0, 0);
}

// ---- 3-bit XOR swizzle for 64-col (128 B row-stride) LDS tiles ----
// granule' = granule ^ (row&7); readers XOR col with ((row&7)<<3) == per-lane
// (ln&7)<<3. (R6: st_16x32 1-bit variant is WRONG for this layout.)

// stage 128x64 bf16 tile into LDS, source pre-swizzled (gl_lds dst linear)
__device__ __forceinline__ void stage_tile(const u16* g, int ld, u16* lds_tile, int tid) {
  int row = tid >> 3, cc = tid & 7;
#pragma unroll
  for (int ri = 0; ri < 4; ri++) {
    int rg = ri * 32 + row;
    gl_lds16(g + (size_t)rg * ld + ((cc ^ (rg & 7)) * 8), &lds_tile[rg * 64 + cc * 8]);
  }
}

// shared 128x128 MFMA inner step over one BK=64 LDS tile pair (256-thr kernels)
__device__ __forceinline__ void mfma_block(const u16* As, const u16* Bs, f32x4 acc[4][4],
                                           int wm, int wn, int ln, int quad) {
  int sw = (ln & 7) << 3;
#pragma unroll
  for (int ks = 0; ks < 2; ks++) {
    bf16x8 af[4], bf[4];
    int co = (ks * 32 + quad * 8) ^ sw;
#pragma unroll
    for (int mt = 0; mt < 4; mt++)
      af[mt] = *(const bf16x8*)&As[(wm * 64 + mt * 16 + ln) * 64 + co];
#pragma unroll
    for (int nt = 0; nt < 4; nt++)
      bf[nt] = *(const bf16x8*)&Bs[(wn * 64 + nt * 16 + ln) * 64 + co];
    __builtin_amdgcn_s_setprio(1);
#pragma unroll
    for (int mt = 0; mt < 4; mt++)
#pragma unroll
      for (int nt = 0; nt < 4; nt++)
        acc[mt][nt] = __builtin_amdgcn_mfma_f32_16x16x32_bf16(af[mt], bf[nt], acc[mt][nt], 0, 0, 0);
    __builtin_amdgcn_s_setprio(0);
  }
}

// ---------------- zero counters ----------------
__global__ void zero_kernel(int* __restrict__ cnt, float* __restrict__ probsum) {
  int i = blockIdx.x * 256 + threadIdx.x;
  if (i < NE) cnt[i] = 0;
  if (i >= NE && i < NE + NE * 64) probsum[i - NE] = 0.f;
}

// ---------------- primitive-bank softmax + top-4 ----------------
__global__ void compose_meta(const float* __restrict__ fc1, const float* __restrict__ fc2,
                             float* __restrict__ sw1, int* __restrict__ idx1,
                             float* __restrict__ sw2, int* __restrict__ idx2) {
  int tid = threadIdx.x;
  if (tid >= 16) return;
  const float* src = (tid < 8) ? fc1 : fc2;
  float* sw = (tid < 8) ? sw1 : sw2;
  int*  idx = (tid < 8) ? idx1 : idx2;
  int e = tid & 7;
  float wv[NP];
  float mx = -1e30f;
  for (int p = 0; p < NP; p++) { wv[p] = src[e * NP + p]; mx = fmaxf(mx, wv[p]); }
  float sum = 0.f;
  for (int p = 0; p < NP; p++) { wv[p] = __expf(wv[p] - mx); sum += wv[p]; }
  float inv = 1.f / sum;
  for (int p = 0; p < NP; p++) wv[p] *= inv;
  float tw[KP]; int ti[KP];
  for (int k = 0; k < KP; k++) {
    int best = 0; float bv = -1.f;
    for (int p = 0; p < NP; p++) if (wv[p] > bv) { bv = wv[p]; best = p; }
    tw[k] = bv; ti[k] = best; wv[best] = -2.f;
  }
  float ts = tw[0] + tw[1] + tw[2] + tw[3];
  float invt = 1.f / (ts + EPSF);
  for (int k = 0; k < KP; k++) {
    sw[e * KP + k] = sqrtf(tw[k] * invt + EPSF);
    idx[e * KP + k] = ti[k];
  }
}

// ---------------- build W1 via LDS transpose (k1 weights, unchanged) --------
__global__ __launch_bounds__(256) void build_AT(
    const float* __restrict__ A, const int* __restrict__ idx,
    const float* __restrict__ sw, u16* __restrict__ W, int D) {
  __shared__ u16 T[64 * 68];
  int ntile = D >> 6;
  int dt = blockIdx.x % ntile;
  int g  = blockIdx.x / ntile;      // e*4+k
  int p = idx[g]; float s = sw[g];
  int d0 = dt * 64;
  int tid = threadIdx.x;
  {
    int rr = (tid & 15) * 4, dd = tid >> 4;
#pragma unroll
    for (int pass = 0; pass < 4; pass++) {
      int d = pass * 16 + dd;
      float4 v = *(const float4*)(A + ((size_t)p * D + d0 + d) * 64 + rr);
      T[(rr + 0) * 68 + d] = f2bf(v.x * s);
      T[(rr + 1) * 68 + d] = f2bf(v.y * s);
      T[(rr + 2) * 68 + d] = f2bf(v.z * s);
      T[(rr + 3) * 68 + d] = f2bf(v.w * s);
    }
  }
  __syncthreads();
  int e = g >> 2, k = g & 3;
  int c = (tid & 15) * 4, r = tid >> 4;
#pragma unroll
  for (int pass = 0; pass < 4; pass++) {
    int rr = pass * 16 + r;
    u16x4v o;
#pragma unroll
    for (int j = 0; j < 4; j++) o[j] = T[rr * 68 + c + j];
    *(u16x4v*)&W[((size_t)e * KR + k * 64 + rr) * D + d0 + c] = o;
  }
}

// ---------------- build V1p: fragment-major packed V1 for k23 phase A ------
// V1p[((((e*16+f0i)*4+p)*4+wv)*2+ks)*2+nt][lane][8] =
//   B1[idx1[e*4+p]][r = ks*32 + (lane>>4)*8 + j][f = f0i*128+wv*32+nt*16+(lane&15)]
//   * sw1[e*4+p]
// One block per (e,f0i,p): coalesced 32KB read -> LDS transpose -> coalesced
// 16B fragment writes. A wave's k23 B-load is then base+lane*16 (1KB, 1 instr).
__global__ __launch_bounds__(256) void build_V1p(
    const float* __restrict__ B1, const int* __restrict__ idx1,
    const float* __restrict__ sw1, u16* __restrict__ V1p) {
  __shared__ u16 Tb[64 * 132];
  int bid = blockIdx.x;
  int p = bid & 3, f0i = (bid >> 2) & 15, e = bid >> 6;
  int prim = idx1[e * 4 + p];
  float s = sw1[e * 4 + p];
  int f0 = f0i * 128;
  int tid = threadIdx.x;
  {
    int r = tid >> 2, fq = (tid & 3) * 32;
#pragma unroll
    for (int q = 0; q < 8; q++) {
      int fl = fq + q * 4;
      float4 v = *(const float4*)(B1 + ((size_t)prim * RANK + r) * DFF + f0 + fl);
      u16x4v o;
      o[0] = f2bf(v.x * s); o[1] = f2bf(v.y * s);
      o[2] = f2bf(v.z * s); o[3] = f2bf(v.w * s);
      *(u16x4v*)&Tb[r * 132 + fl] = o;
    }
  }
  __syncthreads();
  u16* dst = V1p + ((size_t)e << 19) + f0i * 32768 + p * 8192;
#pragma unroll
  for (int it = 0; it < 4; it++) {
    int slot = it * 256 + tid;
    int lane = slot & 63, nt = (slot >> 6) & 1, ks = (slot >> 7) & 1, wv = slot >> 8;
    int ln = lane & 15, quad = lane >> 4;
    int fl = wv * 32 + nt * 16 + ln;
    int r0 = ks * 32 + quad * 8;
    u16x8v o;
#pragma unroll
    for (int j = 0; j < 8; j++) o[j] = Tb[(r0 + j) * 132 + fl];
    *(u16x8v*)&dst[(((wv * 2 + ks) * 2 + nt) * 64 + lane) * 8] = o;
  }
}

// ---------------- build W2p: fragment-major packed W2 for k23 phase B ------
// W2p[((((e*16+f0i)*4+c2)*4+wv)*2+ks)*2+nt][lane][8] =
//   A2[idx2[e*4+k_sel]][f][r]*sw2[..]  with c2 = hh*2+fi,
//   kr = hh*128+wv*32+nt*16+(lane&15), k_sel = hh*2+(wv>>1), r = kr&63,
//   f = f0i*128 + fi*64 + ks*32 + (lane>>4)*8 + j
__global__ __launch_bounds__(256) void build_W2p(
    const float* __restrict__ A2, const int* __restrict__ idx2,
    const float* __restrict__ sw2, u16* __restrict__ W2p) {
  __shared__ u16 Ta[2 * 64 * 68];
  int bid = blockIdx.x;
  int c2 = bid & 3, f0i = (bid >> 2) & 15, e = bid >> 6;
  int hh = c2 >> 1, fi = c2 & 1;
  int f0 = f0i * 128 + fi * 64;
  int tid = threadIdx.x;
  {
    int kk = tid >> 7, row = (tid >> 1) & 63, half = tid & 1;
    int prim = idx2[e * 4 + hh * 2 + kk];
    float s = sw2[e * 4 + hh * 2 + kk];
#pragma unroll
    for (int q = 0; q < 8; q++) {
      int r = half * 32 + q * 4;
      float4 v = *(const float4*)(A2 + ((size_t)prim * DFF + f0 + row) * RANK + r);
      u16x4v o;
      o[0] = f2bf(v.x * s); o[1] = f2bf(v.y * s);
      o[2] = f2bf(v.z * s); o[3] = f2bf(v.w * s);
      *(u16x4v*)&Ta[(kk * 64 + row) * 68 + r] = o;
    }
  }
  __syncthreads();
  u16* dst = W2p + ((size_t)e << 19) + f0i * 32768 + c2 * 8192;
#pragma unroll
  for (int it = 0; it < 4; it++) {
    int slot = it * 256 + tid;
    int lane = slot & 63, nt = (slot >> 6) & 1, ks = (slot >> 7) & 1, wv = slot >> 8;
    int ln = lane & 15, quad = lane >> 4;
    int kk = wv >> 1;
    int r = (wv & 1) * 32 + nt * 16 + ln;
    int fb = ks * 32 + quad * 8;
    u16x8v o;
#pragma unroll
    for (int j = 0; j < 8; j++) o[j] = Ta[(kk * 64 + fb + j) * 68 + r];
    *(u16x8v*)&dst[(((wv * 2 + ks) * 2 + nt) * 64 + lane) * 8] = o;
  }
}

// ---------------- build V2 (k4 weights, linear — unchanged layout) ---------
__global__ void build_V2(const float* __restrict__ B2,
                         const float* __restrict__ sw2, const int* __restrict__ idx2,
                         u16* __restrict__ V2) {
  const int S4 = NE * DM * KR;    // V2[e][d][kr] = B2[p][r][d]*s
  int j = blockIdx.x * 256 + threadIdx.x;
  if (j < S4) {
    int kr = j & 255; int d = (j >> 8) & 511; int e = j >> 17;
    int k = kr >> 6, r = kr & 63; int p = idx2[e * 4 + k];
    V2[j] = f2bf(B2[((size_t)p * RANK + r) * DM + d] * sw2[e * 4 + k]);
  }
}

// ---------------- router, token-per-lane (k-split 4) ----------------
__global__ __launch_bounds__(256) void router_kernel(
    const float* __restrict__ x, const float* __restrict__ Wr,
    float* __restrict__ probsum, int* __restrict__ eidx,
    float* __restrict__ gate) {
  __shared__ float wr_s[NE * 4 * 132];
  __shared__ float ps_s[NE];
  int tid = threadIdx.x;
  if (tid < NE) ps_s[tid] = 0.f;
  for (int i = tid; i < NE * DM; i += 256) {
    int e = i >> 9, k = i & 511;
    wr_s[(e * 4 + (k >> 7)) * 132 + (k & 127)] = Wr[i];
  }
  __syncthreads();
  int lane = tid & 63, wv = tid >> 6;
  int tl = lane & 15, sl = lane >> 4;
  int t = blockIdx.x * 64 + wv * 16 + tl;
  const float* xp = x + (size_t)t * DM + sl * 128;
  const float* wp = &wr_s[sl * 132];
  float acc[NE];
#pragma unroll
  for (int e = 0; e < NE; e++) acc[e] = 0.f;
  for (int c = 0; c < 32; c++) {
    float4 xv = *(const float4*)(xp + c * 4);
#pragma unroll
    for (int e = 0; e < NE; e++) {
      float4 w4 = *(const float4*)(wp + e * 4 * 132 + c * 4);
      acc[e] += xv.x * w4.x + xv.y * w4.y + xv.z * w4.z + xv.w * w4.w;
    }
  }
#pragma unroll
  for (int e = 0; e < NE; e++) {
    acc[e] += __shfl_xor(acc[e], 16, 64);
    acc[e] += __shfl_xor(acc[e], 32, 64);
  }
  if (sl == 0) {
    float mx = acc[0];
#pragma unroll
    for (int e = 1; e < NE; e++) mx = fmaxf(mx, acc[e]);
    float pe[NE]; float sum = 0.f;
#pragma unroll
    for (int e = 0; e < NE; e++) { pe[e] = __expf(acc[e] - mx); sum += pe[e]; }
    float inv = 1.f / sum;
#pragma unroll
    for (int e = 0; e < NE; e++) pe[e] *= inv;
    int i0 = 0;
#pragma unroll
    for (int e = 1; e < NE; e++) if (pe[e] > pe[i0]) i0 = e;
    int i1 = (i0 == 0) ? 1 : 0;
#pragma unroll
    for (int e = 0; e < NE; e++) if (e != i0 && pe[e] > pe[i1]) i1 = e;
    float p0 = pe[i0], p1 = pe[i1];
    float gd = 1.f / (p0 + p1 + EPSF);
    eidx[t] = i0 | (i1 << 3);
    gate[i0 * T_TOK + t] = p0 * gd;
    gate[i1 * T_TOK + t] = p1 * gd;
#pragma unroll
    for (int e = 0; e < NE; e++) atomicAdd(&ps_s[e], pe[e]);
  }
  __syncthreads();
  if (tid < NE) atomicAdd(&probsum[tid * 64 + (blockIdx.x & 63)], ps_s[tid]);
}

// ---------------- scatter (block-aggregated cnt) + per-token slot pairs ----------
__global__ void scatter_kernel(const int* __restrict__ eidx,
                               int* __restrict__ cnt, int* __restrict__ perm,
                               int* __restrict__ slots) {
  __shared__ int hist[NE], base[NE];
  int tid = threadIdx.x;
  if (tid < NE) hist[tid] = 0;
  __syncthreads();
  int t = blockIdx.x * 256 + tid;
  int pk = eidx[t];
  int e0 = pk & 7, e1 = (pk >> 3) & 7;
  int p0 = atomicAdd(&hist[e0], 1);
  int p1 = atomicAdd(&hist[e1], 1);
  __syncthreads();
  if (tid < NE) base[tid] = atomicAdd(&cnt[tid], hist[tid]);
  __syncthreads();
  int g0 = base[e0] + p0; if (g0 >= CAP) g0 = CAP - 1;
  int g1 = base[e1] + p1; if (g1 >= CAP) g1 = CAP - 1;
  perm[e0 * T_TOK + g0] = t;
  perm[e1 * T_TOK + g1] = t;
  slots[t * 2]     = e0 * CAP + g0;
  slots[t * 2 + 1] = e1 * CAP + g1;
}

// ---------------- aux loss (one wave) ----------------
__global__ void aux_kernel(const int* __restrict__ cnt, const float* __restrict__ probsum,
                           float* __restrict__ aux_out) {
  int lane = threadIdx.x;
  if (lane >= 64) return;
  float s[NE];
#pragma unroll
  for (int e = 0; e < NE; e++) {
    float v = probsum[e * 64 + lane];
#pragma unroll
    for (int off = 32; off > 0; off >>= 1) v += __shfl_xor(v, off, 64);
    s[e] = v;
  }
  if (lane == 0) {
    float c[NE]; float cs = 0.f;
    for (int e = 0; e < NE; e++) { c[e] = (float)cnt[e]; cs += c[e]; }
    float aux = 0.f;
    for (int e = 0; e < NE; e++)
      aux += (c[e] / (cs + EPSF)) * (s[e] / (float)T_TOK);
    *aux_out = (float)NE * aux;
  }
}

// ================= FFN pipeline =================
// All FFN kernels decode expert = bid & 7 (XCD affinity, R3-confirmed).

// K1: u[slot,256] = bf16( gather(x) @ A1c )
__global__ __launch_bounds__(256) void k1_u(
    const float* __restrict__ x, const int* __restrict__ cnt,
    const int* __restrict__ perm, const u16* __restrict__ W1,
    u16* __restrict__ u) {
  __shared__ __align__(16) u16 As[8192], Bs[8192];
  __shared__ int tok_s[128];
  int bid = blockIdx.x;
  int e = bid & 7;
  int r0 = bid >> 3;
  int ntile = r0 & 1, mt = r0 >> 1;
  int m0 = mt << 7;
  int cntE = cnt[e];
  if (m0 >= cntE) return;
  int tid = threadIdx.x;
  if (tid < 128) {
    int mm = m0 + tid; if (mm > cntE - 1) mm = cntE - 1;
    tok_s[tid] = perm[e * T_TOK + mm];
  }
  __syncthreads();
  const u16* Bbase = W1 + (size_t)e * KR * DM + (size_t)(ntile * 128) * DM;
  int wv = tid >> 6, lane = tid & 63;
  int wm = wv >> 1, wn = wv & 1, ln = lane & 15, quad = lane >> 4;
  f32x4 acc[4][4];
#pragma unroll
  for (int a = 0; a < 4; a++)
#pragma unroll
    for (int b = 0; b < 4; b++) acc[a][b] = (f32x4){0.f, 0.f, 0.f, 0.f};
  for (int k0 = 0; k0 < DM; k0 += 64) {
    for (int i = tid; i < 2048; i += 256) {
      int row = i >> 4, c4 = i & 15;
      float4 v = *(const float4*)(x + (size_t)tok_s[row] * DM + k0 + c4 * 4);
      u16x4v o; o[0] = f2bf(v.x); o[1] = f2bf(v.y); o[2] = f2bf(v.z); o[3] = f2bf(v.w);
      *(u16x4v*)&As[row * 64 + ((c4 * 4) ^ ((row & 7) << 3))] = o;   // swizzled write
    }
    stage_tile(Bbase + k0, DM, Bs, tid);
    __syncthreads();
    mfma_block(As, Bs, acc, wm, wn, ln, quad);
    __syncthreads();
  }
  int slot0 = e * CAP + m0;
#pragma unroll
  for (int mt2 = 0; mt2 < 4; mt2++)
#pragma unroll
    for (int nt = 0; nt < 4; nt++)
#pragma unroll
      for (int r = 0; r < 4; r++) {
        int row = wm * 64 + mt2 * 16 + quad * 4 + r;
        int col = ntile * 128 + wn * 64 + nt * 16 + ln;
        u[(size_t)(slot0 + row) * KR + col] = f2bf(acc[mt2][nt][r]);
      }
}

// K23 v10: t = gelu(u @ B1c) @ A2c with FRAGMENT-PACKED weights.
// v4-v9 invariant: ~2000 cyc/chunk-step, dominated by the LDS pipe (96
// ds_read_b128/CU-chunk) + 128 barriers for Bs double-buffering. v10 removes
// the B operand from LDS entirely: V1p/W2p are pre-packed in per-lane
// fragment order, so a wave's B load is ONE coalesced global_load_dwordx4
// (1KB) from L2. LDS traffic/chunk halves (A only); barriers drop 128 -> 32
// (only the Hs gelu hazard, 2 per f0i); phase A has NO sync -> compiler
// pipelines B loads under MFMAs. LDS: Us 32K + Hs 16K = 48 KB, 2 blocks/CU.
__global__ __launch_bounds__(256, 2) void k23(
    const u16* __restrict__ u, const int* __restrict__ cnt,
    const u16* __restrict__ V1p, const u16* __restrict__ W2p,
    u16* __restrict__ t) {
  __shared__ __align__(16) u16 Us[64 * 256];      // 32 KB, u tile resident (swizzled)
  __shared__ __align__(16) u16 Hs[64 * 128];      // 16 KB gelu tile (swizzled)
  int bid = blockIdx.x;
  int e = bid & 7, mt = bid >> 3;
  int m0 = mt << 6;
  int cntE = cnt[e];
  if (m0 >= cntE) return;
  int tid = threadIdx.x;
  int slot0 = e * CAP + m0;
  const u16* ub = u + (size_t)slot0 * KR;

  // ---- prologue: stage Us (source pre-swizzled per 512 B row) ----
#pragma unroll
  for (int r = 0; r < 8; r++) {
    int i = r * 256 + tid;                 // 16 B chunk id, 0..2047
    int row = i >> 5, cc = i & 31;
    gl_lds16(ub + (size_t)row * 256 + ((cc ^ (row & 7)) * 8), &Us[i * 8]);
  }
  __syncthreads();                          // drains gl_lds (vmcnt 0)

  int wv = tid >> 6, lane = tid & 63;
  int ln = lane & 15, quad = lane >> 4;
  int sw = (ln & 7) << 3;
  // packed weight bases: [e][f0i][p|c2][wv][ks][nt][lane][8]
  const u16* V1w = V1p + ((size_t)e << 19) + wv * 2048 + lane * 8;
  const u16* W2w = W2p + ((size_t)e << 19) + wv * 2048 + lane * 8;

  f32x4 tacc[4][4];   // [m][hh*2+nt] ; wave wv owns t cols hh*128 + wv*32 + nt*16 + ln
#pragma unroll
  for (int a = 0; a < 4; a++)
#pragma unroll
    for (int b = 0; b < 4; b++) tacc[a][b] = (f32x4){0.f, 0.f, 0.f, 0.f};
  f32x4 hacc[4][2];

  for (int f0i = 0; f0i < 16; f0i++) {
    const u16* V1f = V1w + f0i * 32768;
    const u16* W2f = W2w + f0i * 32768;
    // ---- phase A: h(64x128) += u @ V1 (4 chunks, NO barriers) ----
#pragma unroll
    for (int p = 0; p < 4; p++) {
      bf16x8 bf[2][2], af[2][4];
#pragma unroll
      for (int ks = 0; ks < 2; ks++)
#pragma unroll
        for (int nt = 0; nt < 2; nt++)
          bf[ks][nt] = *(const bf16x8*)&V1f[p * 8192 + (ks * 2 + nt) * 512];
#pragma unroll
      for (int ks = 0; ks < 2; ks++) {
        int cu = (p * 64 + ks * 32 + quad * 8) ^ sw;
#pragma unroll
        for (int m = 0; m < 4; m++)
          af[ks][m] = *(const bf16x8*)&Us[(m * 16 + ln) * 256 + cu];
      }
      if (p == 0) {
#pragma unroll
        for (int a = 0; a < 4; a++)
#pragma unroll
          for (int b = 0; b < 2; b++) hacc[a][b] = (f32x4){0.f, 0.f, 0.f, 0.f};
      }
      __builtin_amdgcn_s_setprio(1);
#pragma unroll
      for (int ks = 0; ks < 2; ks++)
#pragma unroll
        for (int m = 0; m < 4; m++)
#pragma unroll
          for (int nt = 0; nt < 2; nt++)
            hacc[m][nt] = __builtin_amdgcn_mfma_f32_16x16x32_bf16(af[ks][m], bf[ks][nt], hacc[m][nt], 0, 0, 0);
      __builtin_amdgcn_s_setprio(0);
    }
    // ---- barrier 1: all waves done reading PREVIOUS f0i's Hs ----
    __syncthreads();
    // gelu -> Hs (swizzled write matches swizzled read)
#pragma unroll
    for (int m = 0; m < 4; m++)
#pragma unroll
      for (int nt = 0; nt < 2; nt++)
#pragma unroll
        for (int r = 0; r < 4; r++) {
          int row = m * 16 + quad * 4 + r;
          int col = wv * 32 + nt * 16 + ln;
          float v = hacc[m][nt][r];
          float s = 1.f / (1.f + __expf(-1.702f * v));
          Hs[(row << 7) + (col ^ ((row & 7) << 3))] = f2bf(v * s);
        }
    // ---- barrier 2: publish Hs ----
    __syncthreads();
    // ---- phase B: tacc += gelu(h) @ W2 (4 chunks, NO barriers) ----
#pragma unroll
    for (int c2 = 0; c2 < 4; c2++) {
      const int hh = c2 >> 1, fi = c2 & 1;
      bf16x8 bf[2][2], af[2][4];
#pragma unroll
      for (int ks = 0; ks < 2; ks++)
#pragma unroll
        for (int nt = 0; nt < 2; nt++)
          bf[ks][nt] = *(const bf16x8*)&W2f[c2 * 8192 + (ks * 2 + nt) * 512];
#pragma unroll
      for (int ks = 0; ks < 2; ks++) {
        int ch = (fi * 64 + ks * 32 + quad * 8) ^ sw;
#pragma unroll
        for (int m = 0; m < 4; m++)
          af[ks][m] = *(const bf16x8*)&Hs[((m * 16 + ln) << 7) + ch];
      }
      __builtin_amdgcn_s_setprio(1);
#pragma unroll
      for (int ks = 0; ks < 2; ks++)
#pragma unroll
        for (int m = 0; m < 4; m++)
#pragma unroll
          for (int nt = 0; nt < 2; nt++)
            tacc[m][hh * 2 + nt] = __builtin_amdgcn_mfma_f32_16x16x32_bf16(af[ks][m], bf[ks][nt], tacc[m][hh * 2 + nt], 0, 0, 0);
      __builtin_amdgcn_s_setprio(0);
    }
  }
  // epilogue: t (bf16, written once — no RMW)
#pragma unroll
  for (int m = 0; m < 4; m++)
#pragma unroll
    for (int hh = 0; hh < 2; hh++)
#pragma unroll
      for (int nt = 0; nt < 2; nt++)
#pragma unroll
        for (int r = 0; r < 4; r++) {
          int row = m * 16 + quad * 4 + r;
          int col = hh * 128 + wv * 32 + nt * 16 + ln;
          t[(size_t)(slot0 + row) * KR + col] = f2bf(tacc[m][hh * 2 + nt][r]);
        }
}

// K4: y[slot, 512] = gate * (t @ B2c)
__global__ __launch_bounds__(256) void k4_y(
    const u16* __restrict__ t, const int* __restrict__ cnt,
    const int* __restrict__ perm, const float* __restrict__ gate,
    const u16* __restrict__ V2, u16* __restrict__ y) {
  __shared__ __align__(16) u16 As[8192], Bs[8192];
  __shared__ float g_s[128];
  int bid = blockIdx.x;
  int e = bid & 7;
  int r0 = bid >> 3;
  int ntile = r0 & 3, mt = r0 >> 2;
  int m0 = mt << 7;
  int cntE = cnt[e];
  if (m0 >= cntE) return;
  int tid = threadIdx.x;
  if (tid < 128) {
    int mm = m0 + tid; if (mm > cntE - 1) mm = cntE - 1;
    int tk = perm[e * T_TOK + mm];
    g_s[tid] = gate[e * T_TOK + tk];
  }
  __syncthreads();
  int slot0 = e * CAP + m0;
  const u16* Abase = t + (size_t)slot0 * KR;
  const u16* Bbase = V2 + (size_t)e * DM * KR + (size_t)(ntile * 128) * KR;
  int wv = tid >> 6, lane = tid & 63;
  int wm = wv >> 1, wn = wv & 1, ln = lane & 15, quad = lane >> 4;
  f32x4 acc[4][4];
#pragma unroll
  for (int a = 0; a < 4; a++)
#pragma unroll
    for (int b = 0; b < 4; b++) acc[a][b] = (f32x4){0.f, 0.f, 0.f, 0.f};
  for (int k0 = 0; k0 < KR; k0 += 64) {
    stage_tile(Abase + k0, KR, As, tid);
    stage_tile(Bbase + k0, KR, Bs, tid);
    __syncthreads();
    mfma_block(As, Bs, acc, wm, wn, ln, quad);
    __syncthreads();
  }
#pragma unroll
  for (int mt2 = 0; mt2 < 4; mt2++)
#pragma unroll
    for (int nt = 0; nt < 4; nt++)
#pragma unroll
      for (int r = 0; r < 4; r++) {
        int row = wm * 64 + mt2 * 16 + quad * 4 + r;
        int col = ntile * 128 + wn * 64 + nt * 16 + ln;
        y[(size_t)(slot0 + row) * DM + col] = f2bf(acc[mt2][nt][r] * g_s[row]);
      }
}

// gather: out[t] = y[slotA] + y[slotB]
__global__ void gather_kernel(const u16* __restrict__ y, const int* __restrict__ slots,
                              float* __restrict__ out) {
  int idx = blockIdx.x * 256 + threadIdx.x;
  int t = idx >> 7, c4 = (idx & 127) * 4;
  int sA = slots[t * 2], sB = slots[t * 2 + 1];
  u16x4v a = *(const u16x4v*)&y[(size_t)sA * DM + c4];
  u16x4v b = *(const u16x4v*)&y[(size_t)sB * DM + c4];
  float4 o;
  o.x = bf2f(a[0]) + bf2f(b[0]);
  o.y = bf2f(a[1]) + bf2f(b[1]);
  o.z = bf2f(a[2]) + bf2f(b[2]);
  o.w = bf2f(a[3]) + bf2f(b[3]);
  *(float4*)&out[(size_t)t * DM + c4] = o;
}

// ---------------- launch ----------------
extern "C" void kernel_launch(void* const* d_in, const int* in_sizes, int n_in,
                              void* d_out, int out_size, void* d_ws, size_t ws_size,
                              hipStream_t stream) {
  const float* x   = (const float*)d_in[0];
  const float* Wr  = (const float*)d_in[1];
  const float* fc1 = (const float*)d_in[2];
  const float* fc2 = (const float*)d_in[3];
  const float* A1  = (const float*)d_in[4];
  const float* B1  = (const float*)d_in[5];
  const float* A2  = (const float*)d_in[6];
  const float* B2  = (const float*)d_in[7];
  float* out = (float*)d_out;

  char* ws = (char*)d_ws;
  float* sw1     = (float*)(ws + 0);
  int*   idx1    = (int*)(ws + 512);
  float* sw2     = (float*)(ws + 1024);
  int*   idx2    = (int*)(ws + 1536);
  int*   cnt     = (int*)(ws + 2048);
  float* probsum = (float*)(ws + 2560);
  int*   eidx    = (int*)(ws + 8192);                      // 64 KB
  int*   slots   = (int*)(ws + 8192 + 65536);              // 128 KB
  float* gate    = (float*)(ws + 8192 + 65536 + 131072);   // 512 KB
  int*   perm    = (int*)(ws + 8192 + 65536 + 131072 + 524288); // 512 KB
  u16*   W1      = (u16*)(ws + 8192 + 65536 + 131072 + 2 * 524288);
  u16*   V1p     = W1 + 1048576;      // packed V1: 8 x 524288 u16 = 8 MB
  u16*   W2p     = V1p + 4194304;     // packed W2: 8 MB
  u16*   V2      = W2p + 4194304;
  char*  endW    = (char*)(V2 + 1048576);                    // ~22.2 MB
  u16*   u_buf   = (u16*)endW;                               // 49152x256 bf16 = 25.2 MB
  u16*   t_buf   = (u16*)(endW + 25165824);                  // 49152x256 bf16 = 25.2 MB
  u16*   y_buf   = (u16*)(endW + 2 * 25165824);              // 49152x512 bf16 = 50.3 MB
  // total ws use ≈ 123 MB

  zero_kernel<<<3, 256, 0, stream>>>(cnt, probsum);
  compose_meta<<<1, 64, 0, stream>>>(fc1, fc2, sw1, idx1, sw2, idx2);
  build_AT<<<32 * (DM / 64), 256, 0, stream>>>(A1, idx1, sw1, W1, DM);
  build_V1p<<<512, 256, 0, stream>>>(B1, idx1, sw1, V1p);
  build_W2p<<<512, 256, 0, stream>>>(A2, idx2, sw2, W2p);
  build_V2<<<4096, 256, 0, stream>>>(B2, sw2, idx2, V2);
  router_kernel<<<T_TOK / 64, 256, 0, stream>>>(x, Wr, probsum, eidx, gate);
  scatter_kernel<<<T_TOK / 256, 256, 0, stream>>>(eidx, cnt, perm, slots);
  aux_kernel<<<1, 64, 0, stream>>>(cnt, probsum, out + (out_size - 1));

  k1_u<<<2 * NE * MT_E, 256, 0, stream>>>(x, cnt, perm, W1, u_buf);
  k23<<<NE * (CAP / 64), 256, 0, stream>>>(u_buf, cnt, V1p, W2p, t_buf);
  k4_y<<<4 * NE * MT_E, 256, 0, stream>>>(t_buf, cnt, perm, gate, V2, y_buf);
  gather_kernel<<<T_TOK * DM / 4 / 256, 256, 0, stream>>>(y_buf, slots, out);
}

// Round 10
// 355.281 us; speedup vs baseline: 1.3381x; 1.0135x over previous
//
#include <hip/hip_runtime.h>

// ---------------- problem constants ----------------
#define T_TOK 16384
#define DM    512
#define DFF   2048
#define NE    8
#define NP    16
#define KP    4
#define RANK  64
#define KR    256           // KP * RANK
#define EPSF  1e-8f
#define CAP   6144          // per-expert pair capacity (expected ~4096)
#define MT_E  48            // CAP / 128 M-tiles per expert

typedef unsigned short u16;
typedef __bf16 bf16x8 __attribute__((ext_vector_type(8)));
typedef float  f32x4  __attribute__((ext_vector_type(4)));
typedef unsigned short u16x8v __attribute__((ext_vector_type(8)));
typedef unsigned short u16x4v __attribute__((ext_vector_type(4)));

typedef __attribute__((address_space(3))) void as3_void;
typedef __attribute__((address_space(1))) void as1_void;

__device__ __forceinline__ u16 f2bf(float f) {
  return __builtin_bit_cast(u16, (__bf16)f);    // native RTNE cvt (R7)
}
__device__ __forceinline__ float bf2f(u16 v) {
  unsigned int u = ((unsigned int)v) << 16;
  return __builtin_bit_cast(float, u);
}

__device__ __forceinline__ void gl_lds16(const u16* g, u16* l) {
  __builtin_amdgcn_global_load_lds((as1_void*)g, (as3_void*)l, 16, 0, 0);
}

// ---- 3-bit XOR swizzle for 64-col (128 B row-stride) LDS tiles ----
// granule' = granule ^ (row&7); readers XOR col with ((row&7)<<3) == per-lane
// (ln&7)<<3. (R6: st_16x32 1-bit variant is WRONG for this layout.)

// stage 128x64 bf16 tile into LDS, source pre-swizzled (gl_lds dst linear)
__device__ __forceinline__ void stage_tile(const u16* g, int ld, u16* lds_tile, int tid) {
  int row = tid >> 3, cc = tid & 7;
#pragma unroll
  for (int ri = 0; ri < 4; ri++) {
    int rg = ri * 32 + row;
    gl_lds16(g + (size_t)rg * ld + ((cc ^ (rg & 7)) * 8), &lds_tile[rg * 64 + cc * 8]);
  }
}

// ---------------- zero counters ----------------
__global__ void zero_kernel(int* __restrict__ cnt, float* __restrict__ probsum) {
  int i = blockIdx.x * 256 + threadIdx.x;
  if (i < NE) cnt[i] = 0;
  if (i >= NE && i < NE + NE * 64) probsum[i - NE] = 0.f;
}

// ---------------- primitive-bank softmax + top-4 ----------------
__global__ void compose_meta(const float* __restrict__ fc1, const float* __restrict__ fc2,
                             float* __restrict__ sw1, int* __restrict__ idx1,
                             float* __restrict__ sw2, int* __restrict__ idx2) {
  int tid = threadIdx.x;
  if (tid >= 16) return;
  const float* src = (tid < 8) ? fc1 : fc2;
  float* sw = (tid < 8) ? sw1 : sw2;
  int*  idx = (tid < 8) ? idx1 : idx2;
  int e = tid & 7;
  float wv[NP];
  float mx = -1e30f;
  for (int p = 0; p < NP; p++) { wv[p] = src[e * NP + p]; mx = fmaxf(mx, wv[p]); }
  float sum = 0.f;
  for (int p = 0; p < NP; p++) { wv[p] = __expf(wv[p] - mx); sum += wv[p]; }
  float inv = 1.f / sum;
  for (int p = 0; p < NP; p++) wv[p] *= inv;
  float tw[KP]; int ti[KP];
  for (int k = 0; k < KP; k++) {
    int best = 0; float bv = -1.f;
    for (int p = 0; p < NP; p++) if (wv[p] > bv) { bv = wv[p]; best = p; }
    tw[k] = bv; ti[k] = best; wv[best] = -2.f;
  }
  float ts = tw[0] + tw[1] + tw[2] + tw[3];
  float invt = 1.f / (ts + EPSF);
  for (int k = 0; k < KP; k++) {
    sw[e * KP + k] = sqrtf(tw[k] * invt + EPSF);
    idx[e * KP + k] = ti[k];
  }
}

// ---------------- build W1p: fragment-major packed W1 for k1 ---------------
// W1p[((e*2+ntile)*8+k0i)*16 + (wn*2+ks)*4+nt][lane][8] =
//   A1[idx1[e*4+ntile*2+wn]][d = k0i*64+ks*32+(lane>>4)*8+j][r = nt*16+(lane&15)]
//   * sw1[e*4+ntile*2+wn]
__global__ __launch_bounds__(256) void build_W1p(
    const float* __restrict__ A1, const int* __restrict__ idx1,
    const float* __restrict__ sw1, u16* __restrict__ W1p) {
  __shared__ u16 Ta[2 * 64 * 68];
  int bid = blockIdx.x;
  int k0i = bid & 7, ntile = (bid >> 3) & 1, e = bid >> 4;
  int d0 = k0i * 64;
  int tid = threadIdx.x;
  {
    int kk = tid >> 7, row = (tid >> 1) & 63, half = tid & 1;
    int prim = idx1[e * 4 + ntile * 2 + kk];
    float s = sw1[e * 4 + ntile * 2 + kk];
#pragma unroll
    for (int q = 0; q < 8; q++) {
      int r = half * 32 + q * 4;
      float4 v = *(const float4*)(A1 + ((size_t)prim * DM + d0 + row) * RANK + r);
      u16x4v o;
      o[0] = f2bf(v.x * s); o[1] = f2bf(v.y * s);
      o[2] = f2bf(v.z * s); o[3] = f2bf(v.w * s);
      *(u16x4v*)&Ta[(kk * 64 + row) * 68 + r] = o;
    }
  }
  __syncthreads();
  u16* dst = W1p + ((size_t)(e * 2 + ntile) * 8 + k0i) * 8192;
#pragma unroll
  for (int it = 0; it < 4; it++) {
    int slot = it * 256 + tid;
    int lane = slot & 63, rest = slot >> 6;
    int nt = rest & 3, ks = (rest >> 2) & 1, wn = rest >> 3;
    int ln = lane & 15, quad = lane >> 4;
    int r = nt * 16 + ln;
    int db = ks * 32 + quad * 8;
    u16x8v o;
#pragma unroll
    for (int j = 0; j < 8; j++) o[j] = Ta[(wn * 64 + db + j) * 68 + r];
    *(u16x8v*)&dst[((wn * 8 + ks * 4 + nt) * 64 + lane) * 8] = o;
  }
}

// ---------------- build V1p: fragment-major packed V1 for k23 phase A ------
__global__ __launch_bounds__(256) void build_V1p(
    const float* __restrict__ B1, const int* __restrict__ idx1,
    const float* __restrict__ sw1, u16* __restrict__ V1p) {
  __shared__ u16 Tb[64 * 132];
  int bid = blockIdx.x;
  int p = bid & 3, f0i = (bid >> 2) & 15, e = bid >> 6;
  int prim = idx1[e * 4 + p];
  float s = sw1[e * 4 + p];
  int f0 = f0i * 128;
  int tid = threadIdx.x;
  {
    int r = tid >> 2, fq = (tid & 3) * 32;
#pragma unroll
    for (int q = 0; q < 8; q++) {
      int fl = fq + q * 4;
      float4 v = *(const float4*)(B1 + ((size_t)prim * RANK + r) * DFF + f0 + fl);
      u16x4v o;
      o[0] = f2bf(v.x * s); o[1] = f2bf(v.y * s);
      o[2] = f2bf(v.z * s); o[3] = f2bf(v.w * s);
      *(u16x4v*)&Tb[r * 132 + fl] = o;
    }
  }
  __syncthreads();
  u16* dst = V1p + ((size_t)e << 19) + f0i * 32768 + p * 8192;
#pragma unroll
  for (int it = 0; it < 4; it++) {
    int slot = it * 256 + tid;
    int lane = slot & 63, nt = (slot >> 6) & 1, ks = (slot >> 7) & 1, wv = slot >> 8;
    int ln = lane & 15, quad = lane >> 4;
    int fl = wv * 32 + nt * 16 + ln;
    int r0 = ks * 32 + quad * 8;
    u16x8v o;
#pragma unroll
    for (int j = 0; j < 8; j++) o[j] = Tb[(r0 + j) * 132 + fl];
    *(u16x8v*)&dst[(((wv * 2 + ks) * 2 + nt) * 64 + lane) * 8] = o;
  }
}

// ---------------- build W2p: fragment-major packed W2 for k23 phase B ------
__global__ __launch_bounds__(256) void build_W2p(
    const float* __restrict__ A2, const int* __restrict__ idx2,
    const float* __restrict__ sw2, u16* __restrict__ W2p) {
  __shared__ u16 Ta[2 * 64 * 68];
  int bid = blockIdx.x;
  int c2 = bid & 3, f0i = (bid >> 2) & 15, e = bid >> 6;
  int hh = c2 >> 1, fi = c2 & 1;
  int f0 = f0i * 128 + fi * 64;
  int tid = threadIdx.x;
  {
    int kk = tid >> 7, row = (tid >> 1) & 63, half = tid & 1;
    int prim = idx2[e * 4 + hh * 2 + kk];
    float s = sw2[e * 4 + hh * 2 + kk];
#pragma unroll
    for (int q = 0; q < 8; q++) {
      int r = half * 32 + q * 4;
      float4 v = *(const float4*)(A2 + ((size_t)prim * DFF + f0 + row) * RANK + r);
      u16x4v o;
      o[0] = f2bf(v.x * s); o[1] = f2bf(v.y * s);
      o[2] = f2bf(v.z * s); o[3] = f2bf(v.w * s);
      *(u16x4v*)&Ta[(kk * 64 + row) * 68 + r] = o;
    }
  }
  __syncthreads();
  u16* dst = W2p + ((size_t)e << 19) + f0i * 32768 + c2 * 8192;
#pragma unroll
  for (int it = 0; it < 4; it++) {
    int slot = it * 256 + tid;
    int lane = slot & 63, nt = (slot >> 6) & 1, ks = (slot >> 7) & 1, wv = slot >> 8;
    int ln = lane & 15, quad = lane >> 4;
    int kk = wv >> 1;
    int r = (wv & 1) * 32 + nt * 16 + ln;
    int fb = ks * 32 + quad * 8;
    u16x8v o;
#pragma unroll
    for (int j = 0; j < 8; j++) o[j] = Ta[(kk * 64 + fb + j) * 68 + r];
    *(u16x8v*)&dst[(((wv * 2 + ks) * 2 + nt) * 64 + lane) * 8] = o;
  }
}

// ---------------- build V2p: fragment-major packed V2 for k4 ---------------
// V2p[((e*4+ntile)*4+k0i)*16 + (wn*2+ks)*4+nt][lane][8] =
//   B2[idx2[e*4+k0i]][r = ks*32+(lane>>4)*8+j][d = ntile*128+wn*64+nt*16+(lane&15)]
//   * sw2[e*4+k0i]
__global__ __launch_bounds__(256) void build_V2p(
    const float* __restrict__ B2, const int* __restrict__ idx2,
    const float* __restrict__ sw2, u16* __restrict__ V2p) {
  __shared__ u16 Tb[64 * 132];
  int bid = blockIdx.x;
  int k0i = bid & 3, ntile = (bid >> 2) & 3, e = bid >> 4;
  int prim = idx2[e * 4 + k0i];
  float s = sw2[e * 4 + k0i];
  int tid = threadIdx.x;
  {
    int r = tid >> 2, dq = (tid & 3) * 32;
#pragma unroll
    for (int q = 0; q < 8; q++) {
      int dd = dq + q * 4;
      float4 v = *(const float4*)(B2 + ((size_t)prim * RANK + r) * DM + ntile * 128 + dd);
      u16x4v o;
      o[0] = f2bf(v.x * s); o[1] = f2bf(v.y * s);
      o[2] = f2bf(v.z * s); o[3] = f2bf(v.w * s);
      *(u16x4v*)&Tb[r * 132 + dd] = o;
    }
  }
  __syncthreads();
  u16* dst = V2p + ((size_t)(e * 4 + ntile) * 4 + k0i) * 8192;
#pragma unroll
  for (int it = 0; it < 4; it++) {
    int slot = it * 256 + tid;
    int lane = slot & 63, rest = slot >> 6;
    int nt = rest & 3, ks = (rest >> 2) & 1, wn = rest >> 3;
    int ln = lane & 15, quad = lane >> 4;
    int dd = wn * 64 + nt * 16 + ln;
    int r0 = ks * 32 + quad * 8;
    u16x8v o;
#pragma unroll
    for (int j = 0; j < 8; j++) o[j] = Tb[(r0 + j) * 132 + dd];
    *(u16x8v*)&dst[((wn * 8 + ks * 4 + nt) * 64 + lane) * 8] = o;
  }
}

// ---------------- router, token-per-lane (k-split 4) ----------------
__global__ __launch_bounds__(256) void router_kernel(
    const float* __restrict__ x, const float* __restrict__ Wr,
    float* __restrict__ probsum, int* __restrict__ eidx,
    float* __restrict__ gate) {
  __shared__ float wr_s[NE * 4 * 132];
  __shared__ float ps_s[NE];
  int tid = threadIdx.x;
  if (tid < NE) ps_s[tid] = 0.f;
  for (int i = tid; i < NE * DM; i += 256) {
    int e = i >> 9, k = i & 511;
    wr_s[(e * 4 + (k >> 7)) * 132 + (k & 127)] = Wr[i];
  }
  __syncthreads();
  int lane = tid & 63, wv = tid >> 6;
  int tl = lane & 15, sl = lane >> 4;
  int t = blockIdx.x * 64 + wv * 16 + tl;
  const float* xp = x + (size_t)t * DM + sl * 128;
  const float* wp = &wr_s[sl * 132];
  float acc[NE];
#pragma unroll
  for (int e = 0; e < NE; e++) acc[e] = 0.f;
  for (int c = 0; c < 32; c++) {
    float4 xv = *(const float4*)(xp + c * 4);
#pragma unroll
    for (int e = 0; e < NE; e++) {
      float4 w4 = *(const float4*)(wp + e * 4 * 132 + c * 4);
      acc[e] += xv.x * w4.x + xv.y * w4.y + xv.z * w4.z + xv.w * w4.w;
    }
  }
#pragma unroll
  for (int e = 0; e < NE; e++) {
    acc[e] += __shfl_xor(acc[e], 16, 64);
    acc[e] += __shfl_xor(acc[e], 32, 64);
  }
  if (sl == 0) {
    float mx = acc[0];
#pragma unroll
    for (int e = 1; e < NE; e++) mx = fmaxf(mx, acc[e]);
    float pe[NE]; float sum = 0.f;
#pragma unroll
    for (int e = 0; e < NE; e++) { pe[e] = __expf(acc[e] - mx); sum += pe[e]; }
    float inv = 1.f / sum;
#pragma unroll
    for (int e = 0; e < NE; e++) pe[e] *= inv;
    int i0 = 0;
#pragma unroll
    for (int e = 1; e < NE; e++) if (pe[e] > pe[i0]) i0 = e;
    int i1 = (i0 == 0) ? 1 : 0;
#pragma unroll
    for (int e = 0; e < NE; e++) if (e != i0 && pe[e] > pe[i1]) i1 = e;
    float p0 = pe[i0], p1 = pe[i1];
    float gd = 1.f / (p0 + p1 + EPSF);
    eidx[t] = i0 | (i1 << 3);
    gate[i0 * T_TOK + t] = p0 * gd;
    gate[i1 * T_TOK + t] = p1 * gd;
#pragma unroll
    for (int e = 0; e < NE; e++) atomicAdd(&ps_s[e], pe[e]);
  }
  __syncthreads();
  if (tid < NE) atomicAdd(&probsum[tid * 64 + (blockIdx.x & 63)], ps_s[tid]);
}

// ---------------- scatter (block-aggregated cnt) + per-token slot pairs ----------
__global__ void scatter_kernel(const int* __restrict__ eidx,
                               int* __restrict__ cnt, int* __restrict__ perm,
                               int* __restrict__ slots) {
  __shared__ int hist[NE], base[NE];
  int tid = threadIdx.x;
  if (tid < NE) hist[tid] = 0;
  __syncthreads();
  int t = blockIdx.x * 256 + tid;
  int pk = eidx[t];
  int e0 = pk & 7, e1 = (pk >> 3) & 7;
  int p0 = atomicAdd(&hist[e0], 1);
  int p1 = atomicAdd(&hist[e1], 1);
  __syncthreads();
  if (tid < NE) base[tid] = atomicAdd(&cnt[tid], hist[tid]);
  __syncthreads();
  int g0 = base[e0] + p0; if (g0 >= CAP) g0 = CAP - 1;
  int g1 = base[e1] + p1; if (g1 >= CAP) g1 = CAP - 1;
  perm[e0 * T_TOK + g0] = t;
  perm[e1 * T_TOK + g1] = t;
  slots[t * 2]     = e0 * CAP + g0;
  slots[t * 2 + 1] = e1 * CAP + g1;
}

// ---------------- aux loss (one wave) ----------------
__global__ void aux_kernel(const int* __restrict__ cnt, const float* __restrict__ probsum,
                           float* __restrict__ aux_out) {
  int lane = threadIdx.x;
  if (lane >= 64) return;
  float s[NE];
#pragma unroll
  for (int e = 0; e < NE; e++) {
    float v = probsum[e * 64 + lane];
#pragma unroll
    for (int off = 32; off > 0; off >>= 1) v += __shfl_xor(v, off, 64);
    s[e] = v;
  }
  if (lane == 0) {
    float c[NE]; float cs = 0.f;
    for (int e = 0; e < NE; e++) { c[e] = (float)cnt[e]; cs += c[e]; }
    float aux = 0.f;
    for (int e = 0; e < NE; e++)
      aux += (c[e] / (cs + EPSF)) * (s[e] / (float)T_TOK);
    *aux_out = (float)NE * aux;
  }
}

// ================= FFN pipeline =================
// All FFN kernels decode expert = bid & 7 (XCD affinity, R3-confirmed).
// R8 proved: fragment-packed B direct global->register removes B's LDS
// transit + its barriers (k23 220->159 us). R9 applies it to k1 and k4.

// K1 v2: u[slot,256] = bf16( gather(x) @ A1c ), B from packed W1p.
// LDS: As 16 KB only; B fragments issued BEFORE the As barrier (L2 latency
// hides under staging); barriers 16/block (As hazard only).
__global__ __launch_bounds__(256) void k1_u(
    const float* __restrict__ x, const int* __restrict__ cnt,
    const int* __restrict__ perm, const u16* __restrict__ W1p,
    u16* __restrict__ u) {
  __shared__ __align__(16) u16 As[8192];
  __shared__ int tok_s[128];
  int bid = blockIdx.x;
  int e = bid & 7;
  int r0 = bid >> 3;
  int ntile = r0 & 1, mt = r0 >> 1;
  int m0 = mt << 7;
  int cntE = cnt[e];
  if (m0 >= cntE) return;
  int tid = threadIdx.x;
  if (tid < 128) {
    int mm = m0 + tid; if (mm > cntE - 1) mm = cntE - 1;
    tok_s[tid] = perm[e * T_TOK + mm];
  }
  __syncthreads();
  int wv = tid >> 6, lane = tid & 63;
  int wm = wv >> 1, wn = wv & 1, ln = lane & 15, quad = lane >> 4;
  int sw = (ln & 7) << 3;
  const u16* Wbase = W1p + ((size_t)(e * 2 + ntile) * 8) * 8192 + (wn * 8 * 64 + lane) * 8;
  f32x4 acc[4][4];
#pragma unroll
  for (int a = 0; a < 4; a++)
#pragma unroll
    for (int b = 0; b < 4; b++) acc[a][b] = (f32x4){0.f, 0.f, 0.f, 0.f};
  for (int k0i = 0; k0i < 8; k0i++) {
    // B fragments (global, L2-resident) — issue before As stage/barrier
    bf16x8 bf[2][4];
    const u16* Wf = Wbase + (size_t)k0i * 8192;
#pragma unroll
    for (int ks = 0; ks < 2; ks++)
#pragma unroll
      for (int nt = 0; nt < 4; nt++)
        bf[ks][nt] = *(const bf16x8*)&Wf[(ks * 4 + nt) * 512];
    // As stage: gather x rows, cvt, swizzled write
    for (int i = tid; i < 2048; i += 256) {
      int row = i >> 4, c4 = i & 15;
      float4 v = *(const float4*)(x + (size_t)tok_s[row] * DM + k0i * 64 + c4 * 4);
      u16x4v o; o[0] = f2bf(v.x); o[1] = f2bf(v.y); o[2] = f2bf(v.z); o[3] = f2bf(v.w);
      *(u16x4v*)&As[row * 64 + ((c4 * 4) ^ ((row & 7) << 3))] = o;
    }
    __syncthreads();
#pragma unroll
    for (int ks = 0; ks < 2; ks++) {
      bf16x8 af[4];
      int co = (ks * 32 + quad * 8) ^ sw;
#pragma unroll
      for (int mt2 = 0; mt2 < 4; mt2++)
        af[mt2] = *(const bf16x8*)&As[(wm * 64 + mt2 * 16 + ln) * 64 + co];
      __builtin_amdgcn_s_setprio(1);
#pragma unroll
      for (int mt2 = 0; mt2 < 4; mt2++)
#pragma unroll
        for (int nt = 0; nt < 4; nt++)
          acc[mt2][nt] = __builtin_amdgcn_mfma_f32_16x16x32_bf16(af[mt2], bf[ks][nt], acc[mt2][nt], 0, 0, 0);
      __builtin_amdgcn_s_setprio(0);
    }
    __syncthreads();
  }
  int slot0 = e * CAP + m0;
#pragma unroll
  for (int mt2 = 0; mt2 < 4; mt2++)
#pragma unroll
    for (int nt = 0; nt < 4; nt++)
#pragma unroll
      for (int r = 0; r < 4; r++) {
        int row = wm * 64 + mt2 * 16 + quad * 4 + r;
        int col = ntile * 128 + wn * 64 + nt * 16 + ln;
        u[(size_t)(slot0 + row) * KR + col] = f2bf(acc[mt2][nt][r]);
      }
}

// K23 v10 (R8 best): t = gelu(u @ B1c) @ A2c with fragment-packed weights.
// LDS: Us 32K + Hs 16K = 48 KB, 2 blocks/CU; 32 barriers (Hs hazard only).
__global__ __launch_bounds__(256, 2) void k23(
    const u16* __restrict__ u, const int* __restrict__ cnt,
    const u16* __restrict__ V1p, const u16* __restrict__ W2p,
    u16* __restrict__ t) {
  __shared__ __align__(16) u16 Us[64 * 256];      // 32 KB, u tile resident (swizzled)
  __shared__ __align__(16) u16 Hs[64 * 128];      // 16 KB gelu tile (swizzled)
  int bid = blockIdx.x;
  int e = bid & 7, mt = bid >> 3;
  int m0 = mt << 6;
  int cntE = cnt[e];
  if (m0 >= cntE) return;
  int tid = threadIdx.x;
  int slot0 = e * CAP + m0;
  const u16* ub = u + (size_t)slot0 * KR;

  // ---- prologue: stage Us (source pre-swizzled per 512 B row) ----
#pragma unroll
  for (int r = 0; r < 8; r++) {
    int i = r * 256 + tid;                 // 16 B chunk id, 0..2047
    int row = i >> 5, cc = i & 31;
    gl_lds16(ub + (size_t)row * 256 + ((cc ^ (row & 7)) * 8), &Us[i * 8]);
  }
  __syncthreads();                          // drains gl_lds (vmcnt 0)

  int wv = tid >> 6, lane = tid & 63;
  int ln = lane & 15, quad = lane >> 4;
  int sw = (ln & 7) << 3;
  // packed weight bases: [e][f0i][p|c2][wv][ks][nt][lane][8]
  const u16* V1w = V1p + ((size_t)e << 19) + wv * 2048 + lane * 8;
  const u16* W2w = W2p + ((size_t)e << 19) + wv * 2048 + lane * 8;

  f32x4 tacc[4][4];   // [m][hh*2+nt] ; wave wv owns t cols hh*128 + wv*32 + nt*16 + ln
#pragma unroll
  for (int a = 0; a < 4; a++)
#pragma unroll
    for (int b = 0; b < 4; b++) tacc[a][b] = (f32x4){0.f, 0.f, 0.f, 0.f};
  f32x4 hacc[4][2];

  for (int f0i = 0; f0i < 16; f0i++) {
    const u16* V1f = V1w + f0i * 32768;
    const u16* W2f = W2w + f0i * 32768;
    // ---- phase A: h(64x128) += u @ V1 (4 chunks, NO barriers) ----
#pragma unroll
    for (int p = 0; p < 4; p++) {
      bf16x8 bf[2][2], af[2][4];
#pragma unroll
      for (int ks = 0; ks < 2; ks++)
#pragma unroll
        for (int nt = 0; nt < 2; nt++)
          bf[ks][nt] = *(const bf16x8*)&V1f[p * 8192 + (ks * 2 + nt) * 512];
#pragma unroll
      for (int ks = 0; ks < 2; ks++) {
        int cu = (p * 64 + ks * 32 + quad * 8) ^ sw;
#pragma unroll
        for (int m = 0; m < 4; m++)
          af[ks][m] = *(const bf16x8*)&Us[(m * 16 + ln) * 256 + cu];
      }
      if (p == 0) {
#pragma unroll
        for (int a = 0; a < 4; a++)
#pragma unroll
          for (int b = 0; b < 2; b++) hacc[a][b] = (f32x4){0.f, 0.f, 0.f, 0.f};
      }
      __builtin_amdgcn_s_setprio(1);
#pragma unroll
      for (int ks = 0; ks < 2; ks++)
#pragma unroll
        for (int m = 0; m < 4; m++)
#pragma unroll
          for (int nt = 0; nt < 2; nt++)
            hacc[m][nt] = __builtin_amdgcn_mfma_f32_16x16x32_bf16(af[ks][m], bf[ks][nt], hacc[m][nt], 0, 0, 0);
      __builtin_amdgcn_s_setprio(0);
    }
    // ---- barrier 1: all waves done reading PREVIOUS f0i's Hs ----
    __syncthreads();
    // gelu -> Hs (swizzled write matches swizzled read)
#pragma unroll
    for (int m = 0; m < 4; m++)
#pragma unroll
      for (int nt = 0; nt < 2; nt++)
#pragma unroll
        for (int r = 0; r < 4; r++) {
          int row = m * 16 + quad * 4 + r;
          int col = wv * 32 + nt * 16 + ln;
          float v = hacc[m][nt][r];
          float s = 1.f / (1.f + __expf(-1.702f * v));
          Hs[(row << 7) + (col ^ ((row & 7) << 3))] = f2bf(v * s);
        }
    // ---- barrier 2: publish Hs ----
    __syncthreads();
    // ---- phase B: tacc += gelu(h) @ W2 (4 chunks, NO barriers) ----
#pragma unroll
    for (int c2 = 0; c2 < 4; c2++) {
      const int hh = c2 >> 1, fi = c2 & 1;
      bf16x8 bf[2][2], af[2][4];
#pragma unroll
      for (int ks = 0; ks < 2; ks++)
#pragma unroll
        for (int nt = 0; nt < 2; nt++)
          bf[ks][nt] = *(const bf16x8*)&W2f[c2 * 8192 + (ks * 2 + nt) * 512];
#pragma unroll
      for (int ks = 0; ks < 2; ks++) {
        int ch = (fi * 64 + ks * 32 + quad * 8) ^ sw;
#pragma unroll
        for (int m = 0; m < 4; m++)
          af[ks][m] = *(const bf16x8*)&Hs[((m * 16 + ln) << 7) + ch];
      }
      __builtin_amdgcn_s_setprio(1);
#pragma unroll
      for (int ks = 0; ks < 2; ks++)
#pragma unroll
        for (int m = 0; m < 4; m++)
#pragma unroll
          for (int nt = 0; nt < 2; nt++)
            tacc[m][hh * 2 + nt] = __builtin_amdgcn_mfma_f32_16x16x32_bf16(af[ks][m], bf[ks][nt], tacc[m][hh * 2 + nt], 0, 0, 0);
      __builtin_amdgcn_s_setprio(0);
    }
  }
  // epilogue: t (bf16, written once — no RMW)
#pragma unroll
  for (int m = 0; m < 4; m++)
#pragma unroll
    for (int hh = 0; hh < 2; hh++)
#pragma unroll
      for (int nt = 0; nt < 2; nt++)
#pragma unroll
        for (int r = 0; r < 4; r++) {
          int row = m * 16 + quad * 4 + r;
          int col = hh * 128 + wv * 32 + nt * 16 + ln;
          t[(size_t)(slot0 + row) * KR + col] = f2bf(tacc[m][hh * 2 + nt][r]);
        }
}

// K4 v2: y[slot, 512] = gate * (t @ B2c), B from packed V2p.
// LDS: As 16 KB only -> ~6 blocks/CU at grid 1536; 8 barriers/block.
__global__ __launch_bounds__(256) void k4_y(
    const u16* __restrict__ t, const int* __restrict__ cnt,
    const int* __restrict__ perm, const float* __restrict__ gate,
    const u16* __restrict__ V2p, u16* __restrict__ y) {
  __shared__ __align__(16) u16 As[8192];
  __shared__ float g_s[128];
  int bid = blockIdx.x;
  int e = bid & 7;
  int r0 = bid >> 3;
  int ntile = r0 & 3, mt = r0 >> 2;
  int m0 = mt << 7;
  int cntE = cnt[e];
  if (m0 >= cntE) return;
  int tid = threadIdx.x;
  if (tid < 128) {
    int mm = m0 + tid; if (mm > cntE - 1) mm = cntE - 1;
    int tk = perm[e * T_TOK + mm];
    g_s[tid] = gate[e * T_TOK + tk];
  }
  __syncthreads();
  int slot0 = e * CAP + m0;
  const u16* Abase = t + (size_t)slot0 * KR;
  int wv = tid >> 6, lane = tid & 63;
  int wm = wv >> 1, wn = wv & 1, ln = lane & 15, quad = lane >> 4;
  int sw = (ln & 7) << 3;
  const u16* Wbase = V2p + ((size_t)(e * 4 + ntile) * 4) * 8192 + (wn * 8 * 64 + lane) * 8;
  f32x4 acc[4][4];
#pragma unroll
  for (int a = 0; a < 4; a++)
#pragma unroll
    for (int b = 0; b < 4; b++) acc[a][b] = (f32x4){0.f, 0.f, 0.f, 0.f};
  for (int k0i = 0; k0i < 4; k0i++) {
    // B fragments (global, L2) — issue before As stage/barrier
    bf16x8 bf[2][4];
    const u16* Wf = Wbase + (size_t)k0i * 8192;
#pragma unroll
    for (int ks = 0; ks < 2; ks++)
#pragma unroll
      for (int nt = 0; nt < 4; nt++)
        bf[ks][nt] = *(const bf16x8*)&Wf[(ks * 4 + nt) * 512];
    stage_tile(Abase + k0i * 64, KR, As, tid);
    __syncthreads();
#pragma unroll
    for (int ks = 0; ks < 2; ks++) {
      bf16x8 af[4];
      int co = (ks * 32 + quad * 8) ^ sw;
#pragma unroll
      for (int mt2 = 0; mt2 < 4; mt2++)
        af[mt2] = *(const bf16x8*)&As[(wm * 64 + mt2 * 16 + ln) * 64 + co];
      __builtin_amdgcn_s_setprio(1);
#pragma unroll
      for (int mt2 = 0; mt2 < 4; mt2++)
#pragma unroll
        for (int nt = 0; nt < 4; nt++)
          acc[mt2][nt] = __builtin_amdgcn_mfma_f32_16x16x32_bf16(af[mt2], bf[ks][nt], acc[mt2][nt], 0, 0, 0);
      __builtin_amdgcn_s_setprio(0);
    }
    __syncthreads();
  }
#pragma unroll
  for (int mt2 = 0; mt2 < 4; mt2++)
#pragma unroll
    for (int nt = 0; nt < 4; nt++)
#pragma unroll
      for (int r = 0; r < 4; r++) {
        int row = wm * 64 + mt2 * 16 + quad * 4 + r;
        int col = ntile * 128 + wn * 64 + nt * 16 + ln;
        y[(size_t)(slot0 + row) * DM + col] = f2bf(acc[mt2][nt][r] * g_s[row]);
      }
}

// gather: out[t] = y[slotA] + y[slotB]
__global__ void gather_kernel(const u16* __restrict__ y, const int* __restrict__ slots,
                              float* __restrict__ out) {
  int idx = blockIdx.x * 256 + threadIdx.x;
  int t = idx >> 7, c4 = (idx & 127) * 4;
  int sA = slots[t * 2], sB = slots[t * 2 + 1];
  u16x4v a = *(const u16x4v*)&y[(size_t)sA * DM + c4];
  u16x4v b = *(const u16x4v*)&y[(size_t)sB * DM + c4];
  float4 o;
  o.x = bf2f(a[0]) + bf2f(b[0]);
  o.y = bf2f(a[1]) + bf2f(b[1]);
  o.z = bf2f(a[2]) + bf2f(b[2]);
  o.w = bf2f(a[3]) + bf2f(b[3]);
  *(float4*)&out[(size_t)t * DM + c4] = o;
}

// ---------------- launch ----------------
extern "C" void kernel_launch(void* const* d_in, const int* in_sizes, int n_in,
                              void* d_out, int out_size, void* d_ws, size_t ws_size,
                              hipStream_t stream) {
  const float* x   = (const float*)d_in[0];
  const float* Wr  = (const float*)d_in[1];
  const float* fc1 = (const float*)d_in[2];
  const float* fc2 = (const float*)d_in[3];
  const float* A1  = (const float*)d_in[4];
  const float* B1  = (const float*)d_in[5];
  const float* A2  = (const float*)d_in[6];
  const float* B2  = (const float*)d_in[7];
  float* out = (float*)d_out;

  char* ws = (char*)d_ws;
  float* sw1     = (float*)(ws + 0);
  int*   idx1    = (int*)(ws + 512);
  float* sw2     = (float*)(ws + 1024);
  int*   idx2    = (int*)(ws + 1536);
  int*   cnt     = (int*)(ws + 2048);
  float* probsum = (float*)(ws + 2560);
  int*   eidx    = (int*)(ws + 8192);                      // 64 KB
  int*   slots   = (int*)(ws + 8192 + 65536);              // 128 KB
  float* gate    = (float*)(ws + 8192 + 65536 + 131072);   // 512 KB
  int*   perm    = (int*)(ws + 8192 + 65536 + 131072 + 524288); // 512 KB
  u16*   W1p     = (u16*)(ws + 8192 + 65536 + 131072 + 2 * 524288);
  u16*   V1p     = W1p + 1048576;     // packed V1: 8 MB
  u16*   W2p     = V1p + 4194304;     // packed W2: 8 MB
  u16*   V2p     = W2p + 4194304;     // packed V2: 2 MB
  char*  endW    = (char*)(V2p + 1048576);                   // ~22.2 MB
  u16*   u_buf   = (u16*)endW;                               // 49152x256 bf16 = 25.2 MB
  u16*   t_buf   = (u16*)(endW + 25165824);                  // 49152x256 bf16 = 25.2 MB
  u16*   y_buf   = (u16*)(endW + 2 * 25165824);              // 49152x512 bf16 = 50.3 MB
  // total ws use ≈ 123 MB

  zero_kernel<<<3, 256, 0, stream>>>(cnt, probsum);
  compose_meta<<<1, 64, 0, stream>>>(fc1, fc2, sw1, idx1, sw2, idx2);
  build_W1p<<<128, 256, 0, stream>>>(A1, idx1, sw1, W1p);
  build_V1p<<<512, 256, 0, stream>>>(B1, idx1, sw1, V1p);
  build_W2p<<<512, 256, 0, stream>>>(A2, idx2, sw2, W2p);
  build_V2p<<<128, 256, 0, stream>>>(B2, idx2, sw2, V2p);
  router_kernel<<<T_TOK / 64, 256, 0, stream>>>(x, Wr, probsum, eidx, gate);
  scatter_kernel<<<T_TOK / 256, 256, 0, stream>>>(eidx, cnt, perm, slots);
  aux_kernel<<<1, 64, 0, stream>>>(cnt, probsum, out + (out_size - 1));

  k1_u<<<2 * NE * MT_E, 256, 0, stream>>>(x, cnt, perm, W1p, u_buf);
  k23<<<NE * (CAP / 64), 256, 0, stream>>>(u_buf, cnt, V1p, W2p, t_buf);
  k4_y<<<4 * NE * MT_E, 256, 0, stream>>>(t_buf, cnt, perm, gate, V2p, y_buf);
  gather_kernel<<<T_TOK * DM / 4 / 256, 256, 0, stream>>>(y_buf, slots, out);
}